// Round 6
// baseline (1101.502 us; speedup 1.0000x reference)
//
#include <hip/hip_runtime.h>
#include <hip/hip_bf16.h>

#define H 256
#define LN_EPS 1e-5f
#define PITCH 264   // bf16 elements per LDS A-row (256 + 8 pad), 528 B
#define TE 64       // edges per tile (edge kernel)

typedef __attribute__((ext_vector_type(8))) short bf16x8;   // 8 bf16 = 4 VGPRs
typedef __attribute__((ext_vector_type(4))) float f32x4;    // MFMA 16x16 accum

// ---------- helpers ----------
__device__ __forceinline__ float bf2f(unsigned short u) {
  union { unsigned int i; float f; } v; v.i = ((unsigned int)u) << 16; return v.f;
}
__device__ __forceinline__ unsigned short f2bf(float f) {
  union { float f; unsigned int i; } v; v.f = f;
  unsigned int x = v.i;
  return (unsigned short)((x + 0x7fffu + ((x >> 16) & 1u)) >> 16);  // RNE
}
__device__ __forceinline__ void fsplit(float v, unsigned short& hi, unsigned short& lo) {
  hi = f2bf(v);
  lo = f2bf(v - bf2f(hi));
}

// fp32 register-tiled GEMM core (precompute only)
__device__ __forceinline__ void gemm_tile(const float* __restrict__ sA,
                                          const float* __restrict__ W,
                                          int lane_j, int rg, float acc[8][4]) {
#pragma unroll
  for (int mm = 0; mm < 8; mm++)
#pragma unroll
    for (int cc = 0; cc < 4; cc++) acc[mm][cc] = 0.f;
  for (int k = 0; k < H; k += 4) {
    float tvf[8][4];
#pragma unroll
    for (int mm = 0; mm < 8; mm++)
      *(float4*)&tvf[mm][0] = *(const float4*)&sA[(rg * 8 + mm) * H + k];
#pragma unroll
    for (int kk = 0; kk < 4; kk++) {
      const float* wr = W + (k + kk) * H + lane_j;
      float w0 = wr[0], w1 = wr[64], w2 = wr[128], w3 = wr[192];
#pragma unroll
      for (int mm = 0; mm < 8; mm++) {
        float av = tvf[mm][kk];
        acc[mm][0] = fmaf(av, w0, acc[mm][0]);
        acc[mm][1] = fmaf(av, w1, acc[mm][1]);
        acc[mm][2] = fmaf(av, w2, acc[mm][2]);
        acc[mm][3] = fmaf(av, w3, acc[mm][3]);
      }
    }
  }
}

// ---------- precompute kernels ----------

__global__ void k_detect(const int* __restrict__ ei, int* __restrict__ flag) {
  if (threadIdx.x == 0 && blockIdx.x == 0)
    *flag = (ei[1] == 0 && ei[3] == 0 && ei[5] == 0 && ei[7] == 0) ? 1 : 0;
}

__global__ __launch_bounds__(256) void k_zero(float4* __restrict__ p, int n4) {
  int i = blockIdx.x * 256 + threadIdx.x;
  if (i < n4) p[i] = make_float4(0.f, 0.f, 0.f, 0.f);
}

// dst histogram
__global__ __launch_bounds__(256) void k_hist(
    const void* __restrict__ ei, const int* __restrict__ flag64,
    int* __restrict__ hist, int E) {
  int e = blockIdx.x * 256 + threadIdx.x;
  if (e >= E) return;
  int d = (*flag64) ? (int)((const long long*)ei)[(size_t)E + e]
                    : ((const int*)ei)[(size_t)E + e];
  atomicAdd(&hist[d], 1);
}

// exclusive prefix sum over hist[N] -> cursor[N] (single block, 256 threads)
__global__ __launch_bounds__(256) void k_scan(
    const int* __restrict__ hist, int* __restrict__ cursor, int N) {
  __shared__ int part[256];
  int tid = threadIdx.x;
  int chunk = (N + 255) / 256;
  int s = 0;
  for (int i = 0; i < chunk; i++) {
    int idx = tid * chunk + i;
    if (idx < N) s += hist[idx];
  }
  part[tid] = s;
  __syncthreads();
  for (int off = 1; off < 256; off <<= 1) {
    int v = (tid >= off) ? part[tid - off] : 0;
    __syncthreads();
    part[tid] += v;
    __syncthreads();
  }
  int excl = (tid == 0) ? 0 : part[tid - 1];
  for (int i = 0; i < chunk; i++) {
    int idx = tid * chunk + i;
    if (idx < N) {
      cursor[idx] = excl;
      excl += hist[idx];
    }
  }
}

// scatter edges into dst-sorted order (src, dst, edge_attr)
__global__ __launch_bounds__(256) void k_scatter(
    const void* __restrict__ ei, const int* __restrict__ flag64,
    const float* __restrict__ ea, int* __restrict__ cursor,
    int* __restrict__ srcS, int* __restrict__ dstS, float* __restrict__ eaS, int E) {
  int e = blockIdx.x * 256 + threadIdx.x;
  if (e >= E) return;
  int is64 = *flag64;
  int s = is64 ? (int)((const long long*)ei)[e] : ((const int*)ei)[e];
  int d = is64 ? (int)((const long long*)ei)[(size_t)E + e]
               : ((const int*)ei)[(size_t)E + e];
  int p = atomicAdd(&cursor[d], 1);
  srcS[p] = s;
  dstS[p] = d;
  ((float4*)eaS)[p] = ((const float4*)ea)[e];
}

__global__ __launch_bounds__(256) void k_node_proj(
    const float* __restrict__ x, const int* __restrict__ a,
    const float* __restrict__ w, const float* __restrict__ b,
    float* __restrict__ h, int N) {
  int node = blockIdx.x;
  int j = threadIdx.x;
  float acc = b[j];
  acc = fmaf(x[node * 3 + 0], w[0 * H + j], acc);
  acc = fmaf(x[node * 3 + 1], w[1 * H + j], acc);
  acc = fmaf(x[node * 3 + 2], w[2 * H + j], acc);
  acc = fmaf((float)a[node], w[3 * H + j], acc);
  h[(size_t)node * H + j] = fmaxf(acc, 0.f);
}

// WtC[l][j][k] = (em_w2 @ lin_w[l])[k][j], hi/lo bf16 planes
__global__ __launch_bounds__(256, 2) void k_wcomb(
    const float* __restrict__ w2, const float* __restrict__ lin_w,
    unsigned short* __restrict__ wcTh, unsigned short* __restrict__ wcTl) {
  __shared__ __align__(16) float sA[32 * H];
  int l = blockIdx.x >> 3, tile = blockIdx.x & 7;
  int tid = threadIdx.x;
  const float4* src = (const float4*)(w2 + (size_t)tile * 32 * H);
#pragma unroll
  for (int it = 0; it < 8; it++) {
    int vi = it * 256 + tid;
    *(float4*)&sA[vi * 4] = src[vi];
  }
  __syncthreads();
  int lane_j = tid & 63, rg = tid >> 6;
  float acc[8][4];
  gemm_tile(sA, lin_w + (size_t)l * H * H, lane_j, rg, acc);
  unsigned short* oh = wcTh + (size_t)l * H * H;
  unsigned short* ol = wcTl + (size_t)l * H * H;
#pragma unroll
  for (int cc = 0; cc < 4; cc++) {
    int j = lane_j + 64 * cc;
#pragma unroll
    for (int mm = 0; mm < 8; mm++) {
      int k = tile * 32 + rg * 8 + mm;
      unsigned short hi, lo;
      fsplit(acc[mm][cc], hi, lo);
      oh[(size_t)j * H + k] = hi;
      ol[(size_t)j * H + k] = lo;
    }
  }
}

// beta[l] = em_b2 @ lin_w[l] + lin_b[l]
__global__ __launch_bounds__(256) void k_beta(
    const float* __restrict__ lin_w, const float* __restrict__ lin_b,
    const float* __restrict__ b2, float* __restrict__ beta) {
  int l = blockIdx.x, j = threadIdx.x;
  const float* W = lin_w + (size_t)l * H * H;
  float v = lin_b[l * H + j];
  for (int k = 0; k < H; k++) v = fmaf(b2[k], W[k * H + j], v);
  beta[l * H + j] = v;
}

// out_{h,l}[l][n][k] = bf16split(in[l][k][n])
__global__ __launch_bounds__(256) void k_transp(
    const float* __restrict__ in,
    unsigned short* __restrict__ outh, unsigned short* __restrict__ outl) {
  int l = blockIdx.z;
  int kb = blockIdx.x * 64, nb = blockIdx.y * 64;
  int tid = threadIdx.x;
  __shared__ float T[64][65];
  const float* src = in + (size_t)l * H * H;
#pragma unroll
  for (int it = 0; it < 16; it++) {
    int idx = it * 256 + tid;
    int kl = idx >> 6, nl = idx & 63;
    T[kl][nl] = src[(size_t)(kb + kl) * H + nb + nl];
  }
  __syncthreads();
  unsigned short* dh = outh + (size_t)l * H * H;
  unsigned short* dl = outl + (size_t)l * H * H;
#pragma unroll
  for (int it = 0; it < 8; it++) {
    int u = it * 256 + tid;
    int nl = u >> 5, k2 = (u & 31) * 2;
    unsigned short h0, l0, h1, l1;
    fsplit(T[k2][nl], h0, l0);
    fsplit(T[k2 + 1][nl], h1, l1);
    size_t o = (size_t)(nb + nl) * H + kb + k2;
    *(unsigned int*)&dh[o] = (unsigned int)h0 | ((unsigned int)h1 << 16);
    *(unsigned int*)&dl[o] = (unsigned int)l0 | ((unsigned int)l1 << 16);
  }
}

// ---------- per-layer MFMA kernels ----------

// Edge (dst-sorted), tile = TE(64) edges x 256 cols, 8 waves.
// A hi-plane, B hi-plane: e_l = A_hi * B_hi (64 MFMA/wave).
// Epilogue: the acc-owner thread gathers h[src][col] itself and writes
// msg = relu(h + e_l) as bf16 into the full 64-row buffer overlaying the
// A-tile (exact 33.8 KB). No hv[32] register array -> fits the 84-reg cap
// from launch_bounds(512,6) -> 3 blocks/CU (24 waves).
// History: bound 8 => 64-reg cap => spill storm (R2). Bound 4 => 96 regs
// => 2 blocks/CU (R5). Bound 6 is the target point; revert to 4 if
// WRITE_SIZE balloons (spill signature).
__global__ __launch_bounds__(512, 6) void k_edge_mfma(
    const float* __restrict__ eaS,
    const float* __restrict__ w1, const float* __restrict__ b1,
    const unsigned short* __restrict__ Wth,
    const float* __restrict__ beta,
    const float* __restrict__ h, float* __restrict__ agg,
    const int* __restrict__ srcS, const int* __restrict__ dstS) {
  __shared__ __align__(16) unsigned short sAh[TE * PITCH];  // A-tile / bf16 msg-buf
  __shared__ __align__(16) float sEA[TE * 4];
  __shared__ int sSrc[TE];
  __shared__ int sDst[TE];
  int tid = threadIdx.x;
  int base = blockIdx.x * TE;
  if (tid < TE) {
    sSrc[tid] = srcS[base + tid];
  } else if (tid < 2 * TE) {
    sDst[tid - TE] = dstS[base + tid - TE];
  } else if (tid < 3 * TE) {
    int t = tid - 2 * TE;
    ((float4*)sEA)[t] = ((const float4*)(eaS + (size_t)base * 4))[t];
  }
  __syncthreads();
  {  // t = relu(eaS @ w1 + b1) -> bf16 hi plane (col pair, 16 rows/thread)
    int j2 = (tid & 127) * 2;
    int r0 = (tid >> 7) * 16;
    float wv0[4], wv1[4];
#pragma unroll
    for (int q = 0; q < 4; q++) { wv0[q] = w1[q * H + j2]; wv1[q] = w1[q * H + j2 + 1]; }
    float bb0 = b1[j2], bb1 = b1[j2 + 1];
#pragma unroll
    for (int m = r0; m < r0 + 16; m++) {
      float t0 = bb0, t1 = bb1;
#pragma unroll
      for (int q = 0; q < 4; q++) {
        float eav = sEA[m * 4 + q];
        t0 = fmaf(eav, wv0[q], t0);
        t1 = fmaf(eav, wv1[q], t1);
      }
      t0 = fmaxf(t0, 0.f); t1 = fmaxf(t1, 0.f);
      *(unsigned int*)&sAh[m * PITCH + j2] =
          (unsigned int)f2bf(t0) | ((unsigned int)f2bf(t1) << 16);
    }
  }
  __syncthreads();
  int lane = tid & 63, wv = tid >> 6;           // wv in 0..7
  int lane15 = lane & 15, quad = lane >> 4;
  int cg0 = wv * 2;                             // wave's 2 col-groups (32 cols)
  f32x4 acc[4][2];
#pragma unroll
  for (int i = 0; i < 4; i++)
#pragma unroll
    for (int c = 0; c < 2; c++) acc[i][c] = (f32x4){0.f, 0.f, 0.f, 0.f};
  const unsigned short* aph = sAh + lane15 * PITCH + quad * 8;
  const unsigned short* bph = Wth + (size_t)(cg0 * 16 + lane15) * H + quad * 8;
#pragma unroll
  for (int st = 0; st < 8; st++) {
    bf16x8 ah[4];
#pragma unroll
    for (int rg = 0; rg < 4; rg++)
      ah[rg] = *(const bf16x8*)(aph + rg * 16 * PITCH + st * 32);
#pragma unroll
    for (int cg = 0; cg < 2; cg++) {
      bf16x8 bhf = *(const bf16x8*)(bph + (size_t)cg * 16 * H + st * 32);
#pragma unroll
      for (int rg = 0; rg < 4; rg++)
        acc[rg][cg] = __builtin_amdgcn_mfma_f32_16x16x32_bf16(ah[rg], bhf, acc[rg][cg], 0, 0, 0);
    }
  }
  float bv[2];
#pragma unroll
  for (int cg = 0; cg < 2; cg++) bv[cg] = beta[(cg0 + cg) * 16 + lane15];
  __syncthreads();  // all waves done reading A; sAh becomes bf16 msg-buf
  // epilogue: owner thread gathers h[src][col], writes msg = relu(h+e_l) bf16
#pragma unroll
  for (int rg = 0; rg < 4; rg++) {
#pragma unroll
    for (int r = 0; r < 4; r++) {
      int row = rg * 16 + quad * 4 + r;
      int src = sSrc[row];
#pragma unroll
      for (int cg = 0; cg < 2; cg++) {
        int col = (cg0 + cg) * 16 + lane15;
        float m = h[(size_t)src * H + col] + acc[rg][cg][r] + bv[cg];
        sAh[row * PITCH + col] = f2bf(fmaxf(m, 0.f));
      }
    }
  }
  __syncthreads();
  // segment-reduced scatter: thread (half,jcol) walks its 32 dst-sorted rows.
  {
    int jcol = tid & 255, half = tid >> 8;
    const int* mdst = sDst + half * 32;
    float run = 0.f;
    int prev = mdst[0];
#pragma unroll
    for (int m = 0; m < 32; m++) {
      int d = mdst[m];
      float msg = bf2f(sAh[(half * 32 + m) * PITCH + jcol]);
      if (d != prev) {
        atomicAdd(&agg[(size_t)prev * H + jcol], run);
        run = 0.f;
        prev = d;
      }
      run += msg;
    }
    atomicAdd(&agg[(size_t)prev * H + jcol], run);
  }
}

// Node: z=h+agg; z1=relu(z@w1+b1); z2=z1@w2+b2; LN; h += relu(LN).
// Column-slice wave decomposition (wave owns 64 cols x all 64 rows).
// A single bf16 plane AND B single bf16 plane (hi only) on both GEMMs.
__global__ __launch_bounds__(256) void k_node_mfma(
    float* __restrict__ h, const float* __restrict__ agg,
    const unsigned short* __restrict__ w1Th, const float* __restrict__ b1,
    const unsigned short* __restrict__ w2Th, const float* __restrict__ b2,
    const float* __restrict__ lng, const float* __restrict__ lnb) {
  __shared__ __align__(16) unsigned short sAh[64 * PITCH];  // 33792 B
  __shared__ float sPartS[64][4];
  __shared__ float sPartQ[64][4];
  __shared__ float sMu[64];
  __shared__ float sRstd[64];
  int tid = threadIdx.x;
  int base = blockIdx.x * 64;
  const float4* h4 = (const float4*)(h + (size_t)base * H);
  const float4* a4 = (const float4*)(agg + (size_t)base * H);
#pragma unroll
  for (int it = 0; it < 16; it++) {  // all 64 rows (4096 float4)
    int vi = it * 256 + tid;
    int row = vi >> 6, c4 = (vi & 63) * 4;
    float4 hv = h4[vi], av = a4[vi];
    float z[4] = {hv.x + av.x, hv.y + av.y, hv.z + av.z, hv.w + av.w};
    uint2 uh;
    uh.x = (unsigned int)f2bf(z[0]) | ((unsigned int)f2bf(z[1]) << 16);
    uh.y = (unsigned int)f2bf(z[2]) | ((unsigned int)f2bf(z[3]) << 16);
    *(uint2*)&sAh[row * PITCH + c4] = uh;
  }
  __syncthreads();
  int lane = tid & 63, wv = tid >> 6;
  int lane15 = lane & 15, quad = lane >> 4;
  int col0 = wv * 64;                 // wave's 64-col slice
  const unsigned short* aph = sAh + lane15 * PITCH + quad * 8;
  // ---- GEMM1: z1 = relu(z @ w1 + b1), acc[rg][cl]
  f32x4 acc[4][4];
#pragma unroll
  for (int i = 0; i < 4; i++)
#pragma unroll
    for (int c = 0; c < 4; c++) acc[i][c] = (f32x4){0.f, 0.f, 0.f, 0.f};
  {
    const unsigned short* bph = w1Th + (size_t)(col0 + lane15) * H + quad * 8;
#pragma unroll
    for (int st = 0; st < 8; st++) {
      bf16x8 ah[4];
#pragma unroll
      for (int rg = 0; rg < 4; rg++)
        ah[rg] = *(const bf16x8*)(aph + rg * 16 * PITCH + st * 32);
#pragma unroll
      for (int cl = 0; cl < 4; cl++) {
        bf16x8 bhf = *(const bf16x8*)(bph + (size_t)cl * 16 * H + st * 32);
#pragma unroll
        for (int rg = 0; rg < 4; rg++)
          acc[rg][cl] = __builtin_amdgcn_mfma_f32_16x16x32_bf16(ah[rg], bhf, acc[rg][cl], 0, 0, 0);
      }
    }
  }
  float b1v[4];
#pragma unroll
  for (int cl = 0; cl < 4; cl++) b1v[cl] = b1[col0 + cl * 16 + lane15];
  __syncthreads();  // all waves done reading z
#pragma unroll
  for (int rg = 0; rg < 4; rg++)
#pragma unroll
    for (int r = 0; r < 4; r++) {
      int row = rg * 16 + quad * 4 + r;
#pragma unroll
      for (int cl = 0; cl < 4; cl++) {
        int col = col0 + cl * 16 + lane15;
        sAh[row * PITCH + col] = f2bf(fmaxf(acc[rg][cl][r] + b1v[cl], 0.f));
      }
    }
  __syncthreads();
  // ---- GEMM2: z2 = z1 @ w2 + b2, acc2[rg][cl]
  f32x4 acc2[4][4];
#pragma unroll
  for (int i = 0; i < 4; i++)
#pragma unroll
    for (int c = 0; c < 4; c++) acc2[i][c] = (f32x4){0.f, 0.f, 0.f, 0.f};
  {
    const unsigned short* bph = w2Th + (size_t)(col0 + lane15) * H + quad * 8;
#pragma unroll
    for (int st = 0; st < 8; st++) {
      bf16x8 ah[4];
#pragma unroll
      for (int rg = 0; rg < 4; rg++)
        ah[rg] = *(const bf16x8*)(aph + rg * 16 * PITCH + st * 32);
#pragma unroll
      for (int cl = 0; cl < 4; cl++) {
        bf16x8 bhf = *(const bf16x8*)(bph + (size_t)cl * 16 * H + st * 32);
#pragma unroll
        for (int rg = 0; rg < 4; rg++)
          acc2[rg][cl] = __builtin_amdgcn_mfma_f32_16x16x32_bf16(ah[rg], bhf, acc2[rg][cl], 0, 0, 0);
      }
    }
  }
  float b2v[4], gv[4], bbv[4];
#pragma unroll
  for (int cl = 0; cl < 4; cl++) {
    int col = col0 + cl * 16 + lane15;
    b2v[cl] = b2[col]; gv[cl] = lng[col]; bbv[cl] = lnb[col];
  }
  // ---- LN partials: per row, reduce this wave's 64 cols
#pragma unroll
  for (int rg = 0; rg < 4; rg++)
#pragma unroll
    for (int r = 0; r < 4; r++) {
      int row = rg * 16 + quad * 4 + r;
      float s = 0.f, ss = 0.f;
#pragma unroll
      for (int cl = 0; cl < 4; cl++) {
        float z2 = acc2[rg][cl][r] + b2v[cl];
        s += z2;
        ss = fmaf(z2, z2, ss);
      }
      s += __shfl_xor(s, 1, 64); ss += __shfl_xor(ss, 1, 64);
      s += __shfl_xor(s, 2, 64); ss += __shfl_xor(ss, 2, 64);
      s += __shfl_xor(s, 4, 64); ss += __shfl_xor(ss, 4, 64);
      s += __shfl_xor(s, 8, 64); ss += __shfl_xor(ss, 8, 64);
      if (lane15 == 0) { sPartS[row][wv] = s; sPartQ[row][wv] = ss; }
    }
  __syncthreads();
  if (tid < 64) {
    float s = sPartS[tid][0] + sPartS[tid][1] + sPartS[tid][2] + sPartS[tid][3];
    float ss = sPartQ[tid][0] + sPartQ[tid][1] + sPartQ[tid][2] + sPartQ[tid][3];
    float mu = s * (1.f / H);
    float var = ss * (1.f / H) - mu * mu;
    sMu[tid] = mu;
    sRstd[tid] = rsqrtf(var + LN_EPS);
  }
  __syncthreads();
  // ---- apply LN + residual
#pragma unroll
  for (int rg = 0; rg < 4; rg++)
#pragma unroll
    for (int r = 0; r < 4; r++) {
      int row = rg * 16 + quad * 4 + r;
      float mu = sMu[row], rstd = sRstd[row];
      float* hr = h + (size_t)(base + row) * H;
#pragma unroll
      for (int cl = 0; cl < 4; cl++) {
        int col = col0 + cl * 16 + lane15;
        float z2 = acc2[rg][cl][r] + b2v[cl];
        float v = fmaf((z2 - mu) * rstd, gv[cl], bbv[cl]);
        hr[col] = hr[col] + fmaxf(v, 0.f);
      }
    }
}

// Partial mean-pool: block sums 64 rows into g[b][.] via atomics (fully parallel).
__global__ __launch_bounds__(256) void k_pool(
    const float* __restrict__ h, float* __restrict__ g, int n) {
  int tid = threadIdx.x;
  int row0 = blockIdx.x * 64;
  int b = row0 / n;                       // 64 | n, block never straddles graphs
  const float* hb = h + (size_t)row0 * H;
  float s0 = 0.f, s1 = 0.f, s2 = 0.f, s3 = 0.f;
  for (int i = 0; i < 64; i += 4) {
    s0 += hb[(size_t)(i + 0) * H + tid];
    s1 += hb[(size_t)(i + 1) * H + tid];
    s2 += hb[(size_t)(i + 2) * H + tid];
    s3 += hb[(size_t)(i + 3) * H + tid];
  }
  atomicAdd(&g[(size_t)b * H + tid], s0 + s1 + s2 + s3);
}

// Head MLP from pooled g. One block per graph.
__global__ __launch_bounds__(256) void k_head(
    const float* __restrict__ g,
    const float* __restrict__ w1, const float* __restrict__ b1,
    const float* __restrict__ w2, const float* __restrict__ b2,
    float* __restrict__ out, int n) {
  __shared__ float sG[H];
  __shared__ float sT[H];
  __shared__ float sR[4];
  int b = blockIdx.x, tid = threadIdx.x;
  sG[tid] = g[(size_t)b * H + tid] / (float)n;
  __syncthreads();
  float t = b1[tid];
  for (int k = 0; k < H; k++) t = fmaf(sG[k], w1[k * H + tid], t);
  sT[tid] = fmaxf(t, 0.f);
  __syncthreads();
  float p = sT[tid] * w2[tid];
#pragma unroll
  for (int off = 32; off > 0; off >>= 1) p += __shfl_xor(p, off, 64);
  if ((tid & 63) == 0) sR[tid >> 6] = p;
  __syncthreads();
  if (tid == 0) out[b] = sR[0] + sR[1] + sR[2] + sR[3] + b2[0];
}

// ---------- launcher ----------
extern "C" void kernel_launch(void* const* d_in, const int* in_sizes, int n_in,
                              void* d_out, int out_size, void* d_ws, size_t ws_size,
                              hipStream_t stream) {
  const float* x      = (const float*)d_in[0];
  const float* ea     = (const float*)d_in[1];
  const void*  ei     = d_in[2];
  const int*   a      = (const int*)d_in[3];
  const float* np_w   = (const float*)d_in[4];
  const float* np_b   = (const float*)d_in[5];
  const float* em_w1  = (const float*)d_in[6];
  const float* em_b1  = (const float*)d_in[7];
  const float* em_w2  = (const float*)d_in[8];
  const float* em_b2  = (const float*)d_in[9];
  const float* lin_w  = (const float*)d_in[10];
  const float* lin_b  = (const float*)d_in[11];
  const float* m_w1   = (const float*)d_in[12];
  const float* m_b1   = (const float*)d_in[13];
  const float* m_w2   = (const float*)d_in[14];
  const float* m_b2   = (const float*)d_in[15];
  const float* ln_g   = (const float*)d_in[16];
  const float* ln_b   = (const float*)d_in[17];
  const float* hd_w1  = (const float*)d_in[18];
  const float* hd_b1  = (const float*)d_in[19];
  const float* hd_w2  = (const float*)d_in[20];
  const float* hd_b2  = (const float*)d_in[21];

  int N = in_sizes[0] / 3;
  int E = in_sizes[1] / 4;
  int B = out_size;
  int n = N / B;

  // workspace layout (~82 MB)
  char* ws = (char*)d_ws;
  size_t off = 0;
  auto alloc = [&](size_t bytes) {
    char* p = ws + off;
    off += (bytes + 255) & ~(size_t)255;
    return p;
  };
  float* h    = (float*)alloc((size_t)N * H * 4);
  float* agg  = (float*)alloc((size_t)N * H * 4);
  unsigned short* wcTh = (unsigned short*)alloc((size_t)3 * H * H * 2);
  unsigned short* wcTl = (unsigned short*)alloc((size_t)3 * H * H * 2);
  unsigned short* w1Th = (unsigned short*)alloc((size_t)3 * H * H * 2);
  unsigned short* w1Tl = (unsigned short*)alloc((size_t)3 * H * H * 2);
  unsigned short* w2Th = (unsigned short*)alloc((size_t)3 * H * H * 2);
  unsigned short* w2Tl = (unsigned short*)alloc((size_t)3 * H * H * 2);
  float* beta  = (float*)alloc(3 * H * 4);
  int*   flag  = (int*)alloc(4);
  int*   hist  = (int*)alloc((size_t)N * 4);
  int*   curs  = (int*)alloc((size_t)N * 4);
  int*   srcS  = (int*)alloc((size_t)E * 4);
  int*   dstS  = (int*)alloc((size_t)E * 4);
  float* eaS   = (float*)alloc((size_t)E * 4 * 4);
  float* g     = (float*)alloc((size_t)B * H * 4);

  float* out = (float*)d_out;
  int ebl = (E + 255) / 256;

  k_detect<<<1, 64, 0, stream>>>((const int*)ei, flag);
  k_zero<<<(N + 1023) / 1024, 256, 0, stream>>>((float4*)hist, N / 4);
  k_hist<<<ebl, 256, 0, stream>>>(ei, flag, hist, E);
  k_scan<<<1, 256, 0, stream>>>(hist, curs, N);
  k_scatter<<<ebl, 256, 0, stream>>>(ei, flag, ea, curs, srcS, dstS, eaS, E);
  k_node_proj<<<N, 256, 0, stream>>>(x, a, np_w, np_b, h, N);
  k_wcomb<<<24, 256, 0, stream>>>(em_w2, lin_w, wcTh, wcTl);
  k_beta<<<3, 256, 0, stream>>>(lin_w, lin_b, em_b2, beta);
  k_transp<<<dim3(4, 4, 3), 256, 0, stream>>>(m_w1, w1Th, w1Tl);
  k_transp<<<dim3(4, 4, 3), 256, 0, stream>>>(m_w2, w2Th, w2Tl);

  int n4 = N * H / 4;
  for (int l = 0; l < 3; l++) {
    k_zero<<<(n4 + 255) / 256, 256, 0, stream>>>((float4*)agg, n4);
    k_edge_mfma<<<E / TE, 512, 0, stream>>>(eaS, em_w1, em_b1,
                                            wcTh + (size_t)l * H * H,
                                            beta + (size_t)l * H,
                                            h, agg, srcS, dstS);
    k_node_mfma<<<N / 64, 256, 0, stream>>>(h, agg,
                                            w1Th + (size_t)l * H * H,
                                            m_b1 + (size_t)l * H,
                                            w2Th + (size_t)l * H * H,
                                            m_b2 + (size_t)l * H,
                                            ln_g + (size_t)l * H, ln_b + (size_t)l * H);
  }
  int g4 = B * H / 4;
  k_zero<<<(g4 + 255) / 256, 256, 0, stream>>>((float4*)g, g4);
  k_pool<<<N / 64, 256, 0, stream>>>(h, g, n);
  k_head<<<B, 256, 0, stream>>>(g, hd_w1, hd_b1, hd_w2, hd_b2, out, n);
}

// Round 7
// 1025.956 us; speedup vs baseline: 1.0736x; 1.0736x over previous
//
#include <hip/hip_runtime.h>
#include <hip/hip_bf16.h>

#define H 256
#define LN_EPS 1e-5f
#define PITCH 264   // bf16 elements per LDS A-row (256 + 8 pad), 528 B
#define TE 64       // edges per tile (edge kernel)

typedef __attribute__((ext_vector_type(8))) short bf16x8;   // 8 bf16 = 4 VGPRs
typedef __attribute__((ext_vector_type(4))) float f32x4;    // MFMA 16x16 accum

// ---------- helpers ----------
__device__ __forceinline__ float bf2f(unsigned short u) {
  union { unsigned int i; float f; } v; v.i = ((unsigned int)u) << 16; return v.f;
}
__device__ __forceinline__ unsigned short f2bf(float f) {
  union { float f; unsigned int i; } v; v.f = f;
  unsigned int x = v.i;
  return (unsigned short)((x + 0x7fffu + ((x >> 16) & 1u)) >> 16);  // RNE
}
// packed pair: low 16 = a, high 16 = b (RNE, single v_cvt_pk_bf16_f32)
__device__ __forceinline__ unsigned int pack2bf(float a, float b) {
  __hip_bfloat162 t = __float22bfloat162_rn(make_float2(a, b));
  unsigned int u;
  __builtin_memcpy(&u, &t, 4);
  return u;
}
__device__ __forceinline__ void fsplit(float v, unsigned short& hi, unsigned short& lo) {
  hi = f2bf(v);
  lo = f2bf(v - bf2f(hi));
}

// fp32 register-tiled GEMM core (precompute only)
__device__ __forceinline__ void gemm_tile(const float* __restrict__ sA,
                                          const float* __restrict__ W,
                                          int lane_j, int rg, float acc[8][4]) {
#pragma unroll
  for (int mm = 0; mm < 8; mm++)
#pragma unroll
    for (int cc = 0; cc < 4; cc++) acc[mm][cc] = 0.f;
  for (int k = 0; k < H; k += 4) {
    float tvf[8][4];
#pragma unroll
    for (int mm = 0; mm < 8; mm++)
      *(float4*)&tvf[mm][0] = *(const float4*)&sA[(rg * 8 + mm) * H + k];
#pragma unroll
    for (int kk = 0; kk < 4; kk++) {
      const float* wr = W + (k + kk) * H + lane_j;
      float w0 = wr[0], w1 = wr[64], w2 = wr[128], w3 = wr[192];
#pragma unroll
      for (int mm = 0; mm < 8; mm++) {
        float av = tvf[mm][kk];
        acc[mm][0] = fmaf(av, w0, acc[mm][0]);
        acc[mm][1] = fmaf(av, w1, acc[mm][1]);
        acc[mm][2] = fmaf(av, w2, acc[mm][2]);
        acc[mm][3] = fmaf(av, w3, acc[mm][3]);
      }
    }
  }
}

// ---------- precompute kernels ----------

__global__ void k_detect(const int* __restrict__ ei, int* __restrict__ flag) {
  if (threadIdx.x == 0 && blockIdx.x == 0)
    *flag = (ei[1] == 0 && ei[3] == 0 && ei[5] == 0 && ei[7] == 0) ? 1 : 0;
}

__global__ __launch_bounds__(256) void k_zero(float4* __restrict__ p, int n4) {
  int i = blockIdx.x * 256 + threadIdx.x;
  if (i < n4) p[i] = make_float4(0.f, 0.f, 0.f, 0.f);
}

// dst histogram
__global__ __launch_bounds__(256) void k_hist(
    const void* __restrict__ ei, const int* __restrict__ flag64,
    int* __restrict__ hist, int E) {
  int e = blockIdx.x * 256 + threadIdx.x;
  if (e >= E) return;
  int d = (*flag64) ? (int)((const long long*)ei)[(size_t)E + e]
                    : ((const int*)ei)[(size_t)E + e];
  atomicAdd(&hist[d], 1);
}

// exclusive prefix sum over hist[N] -> cursor[N] (single block, 256 threads)
__global__ __launch_bounds__(256) void k_scan(
    const int* __restrict__ hist, int* __restrict__ cursor, int N) {
  __shared__ int part[256];
  int tid = threadIdx.x;
  int chunk = (N + 255) / 256;
  int s = 0;
  for (int i = 0; i < chunk; i++) {
    int idx = tid * chunk + i;
    if (idx < N) s += hist[idx];
  }
  part[tid] = s;
  __syncthreads();
  for (int off = 1; off < 256; off <<= 1) {
    int v = (tid >= off) ? part[tid - off] : 0;
    __syncthreads();
    part[tid] += v;
    __syncthreads();
  }
  int excl = (tid == 0) ? 0 : part[tid - 1];
  for (int i = 0; i < chunk; i++) {
    int idx = tid * chunk + i;
    if (idx < N) {
      cursor[idx] = excl;
      excl += hist[idx];
    }
  }
}

// scatter edges into dst-sorted order (src, dst, edge_attr)
__global__ __launch_bounds__(256) void k_scatter(
    const void* __restrict__ ei, const int* __restrict__ flag64,
    const float* __restrict__ ea, int* __restrict__ cursor,
    int* __restrict__ srcS, int* __restrict__ dstS, float* __restrict__ eaS, int E) {
  int e = blockIdx.x * 256 + threadIdx.x;
  if (e >= E) return;
  int is64 = *flag64;
  int s = is64 ? (int)((const long long*)ei)[e] : ((const int*)ei)[e];
  int d = is64 ? (int)((const long long*)ei)[(size_t)E + e]
               : ((const int*)ei)[(size_t)E + e];
  int p = atomicAdd(&cursor[d], 1);
  srcS[p] = s;
  dstS[p] = d;
  ((float4*)eaS)[p] = ((const float4*)ea)[e];
}

__global__ __launch_bounds__(256) void k_node_proj(
    const float* __restrict__ x, const int* __restrict__ a,
    const float* __restrict__ w, const float* __restrict__ b,
    float* __restrict__ h, int N) {
  int node = blockIdx.x;
  int j = threadIdx.x;
  float acc = b[j];
  acc = fmaf(x[node * 3 + 0], w[0 * H + j], acc);
  acc = fmaf(x[node * 3 + 1], w[1 * H + j], acc);
  acc = fmaf(x[node * 3 + 2], w[2 * H + j], acc);
  acc = fmaf((float)a[node], w[3 * H + j], acc);
  h[(size_t)node * H + j] = fmaxf(acc, 0.f);
}

// WtC[l][j][k] = (em_w2 @ lin_w[l])[k][j], hi/lo bf16 planes
__global__ __launch_bounds__(256, 2) void k_wcomb(
    const float* __restrict__ w2, const float* __restrict__ lin_w,
    unsigned short* __restrict__ wcTh, unsigned short* __restrict__ wcTl) {
  __shared__ __align__(16) float sA[32 * H];
  int l = blockIdx.x >> 3, tile = blockIdx.x & 7;
  int tid = threadIdx.x;
  const float4* src = (const float4*)(w2 + (size_t)tile * 32 * H);
#pragma unroll
  for (int it = 0; it < 8; it++) {
    int vi = it * 256 + tid;
    *(float4*)&sA[vi * 4] = src[vi];
  }
  __syncthreads();
  int lane_j = tid & 63, rg = tid >> 6;
  float acc[8][4];
  gemm_tile(sA, lin_w + (size_t)l * H * H, lane_j, rg, acc);
  unsigned short* oh = wcTh + (size_t)l * H * H;
  unsigned short* ol = wcTl + (size_t)l * H * H;
#pragma unroll
  for (int cc = 0; cc < 4; cc++) {
    int j = lane_j + 64 * cc;
#pragma unroll
    for (int mm = 0; mm < 8; mm++) {
      int k = tile * 32 + rg * 8 + mm;
      unsigned short hi, lo;
      fsplit(acc[mm][cc], hi, lo);
      oh[(size_t)j * H + k] = hi;
      ol[(size_t)j * H + k] = lo;
    }
  }
}

// beta[l] = em_b2 @ lin_w[l] + lin_b[l]
__global__ __launch_bounds__(256) void k_beta(
    const float* __restrict__ lin_w, const float* __restrict__ lin_b,
    const float* __restrict__ b2, float* __restrict__ beta) {
  int l = blockIdx.x, j = threadIdx.x;
  const float* W = lin_w + (size_t)l * H * H;
  float v = lin_b[l * H + j];
  for (int k = 0; k < H; k++) v = fmaf(b2[k], W[k * H + j], v);
  beta[l * H + j] = v;
}

// out_{h,l}[l][n][k] = bf16split(in[l][k][n])
__global__ __launch_bounds__(256) void k_transp(
    const float* __restrict__ in,
    unsigned short* __restrict__ outh, unsigned short* __restrict__ outl) {
  int l = blockIdx.z;
  int kb = blockIdx.x * 64, nb = blockIdx.y * 64;
  int tid = threadIdx.x;
  __shared__ float T[64][65];
  const float* src = in + (size_t)l * H * H;
#pragma unroll
  for (int it = 0; it < 16; it++) {
    int idx = it * 256 + tid;
    int kl = idx >> 6, nl = idx & 63;
    T[kl][nl] = src[(size_t)(kb + kl) * H + nb + nl];
  }
  __syncthreads();
  unsigned short* dh = outh + (size_t)l * H * H;
  unsigned short* dl = outl + (size_t)l * H * H;
#pragma unroll
  for (int it = 0; it < 8; it++) {
    int u = it * 256 + tid;
    int nl = u >> 5, k2 = (u & 31) * 2;
    unsigned short h0, l0, h1, l1;
    fsplit(T[k2][nl], h0, l0);
    fsplit(T[k2 + 1][nl], h1, l1);
    size_t o = (size_t)(nb + nl) * H + kb + k2;
    *(unsigned int*)&dh[o] = (unsigned int)h0 | ((unsigned int)h1 << 16);
    *(unsigned int*)&dl[o] = (unsigned int)l0 | ((unsigned int)l1 << 16);
  }
}

// ---------- per-layer MFMA kernels ----------

// Edge (dst-sorted), tile = TE(64) edges x 256 cols, 8 waves.
// A hi-plane, B hi-plane: e_l = A_hi * B_hi (64 MFMA/wave).
// Epilogue (R7): R5's COALESCED jcol-gather restored (one 256B-contiguous run
// per row per wave, issued BEFORE the barrier so loads drain under the
// elbuf-write phase), but h held as PACKED bf16 pairs hvp[16] (was hv[32] f32)
// to fit the 85-reg cap of launch_bounds(512,6) -> keeps 3 blocks/CU.
// History: bound 8 => spill storm (R2). bound 4 + hv[32] => 96 regs, 2 blk/CU
// (R5). bound 6 + owner-gather => 66% occ but uncoalesced+serialized gather,
// net regression (R6). This round: coalesced gather + packed regs + bound 6.
__global__ __launch_bounds__(512, 6) void k_edge_mfma(
    const float* __restrict__ eaS,
    const float* __restrict__ w1, const float* __restrict__ b1,
    const unsigned short* __restrict__ Wth,
    const float* __restrict__ beta,
    const float* __restrict__ h, float* __restrict__ agg,
    const int* __restrict__ srcS, const int* __restrict__ dstS) {
  __shared__ __align__(16) unsigned short sAh[TE * PITCH];  // A-tile / bf16 elbuf
  __shared__ __align__(16) float sEA[TE * 4];
  __shared__ int sSrc[TE];
  __shared__ int sDst[TE];
  int tid = threadIdx.x;
  int base = blockIdx.x * TE;
  if (tid < TE) {
    sSrc[tid] = srcS[base + tid];
  } else if (tid < 2 * TE) {
    sDst[tid - TE] = dstS[base + tid - TE];
  } else if (tid < 3 * TE) {
    int t = tid - 2 * TE;
    ((float4*)sEA)[t] = ((const float4*)(eaS + (size_t)base * 4))[t];
  }
  __syncthreads();
  {  // t = relu(eaS @ w1 + b1) -> bf16 hi plane (col pair, 16 rows/thread)
    int j2 = (tid & 127) * 2;
    int r0 = (tid >> 7) * 16;
    float wv0[4], wv1[4];
#pragma unroll
    for (int q = 0; q < 4; q++) { wv0[q] = w1[q * H + j2]; wv1[q] = w1[q * H + j2 + 1]; }
    float bb0 = b1[j2], bb1 = b1[j2 + 1];
#pragma unroll
    for (int m = r0; m < r0 + 16; m++) {
      float t0 = bb0, t1 = bb1;
#pragma unroll
      for (int q = 0; q < 4; q++) {
        float eav = sEA[m * 4 + q];
        t0 = fmaf(eav, wv0[q], t0);
        t1 = fmaf(eav, wv1[q], t1);
      }
      *(unsigned int*)&sAh[m * PITCH + j2] = pack2bf(fmaxf(t0, 0.f), fmaxf(t1, 0.f));
    }
  }
  __syncthreads();
  int lane = tid & 63, wv = tid >> 6;           // wv in 0..7
  int lane15 = lane & 15, quad = lane >> 4;
  int cg0 = wv * 2;                             // wave's 2 col-groups (32 cols)
  f32x4 acc[4][2];
#pragma unroll
  for (int i = 0; i < 4; i++)
#pragma unroll
    for (int c = 0; c < 2; c++) acc[i][c] = (f32x4){0.f, 0.f, 0.f, 0.f};
  const unsigned short* aph = sAh + lane15 * PITCH + quad * 8;
  const unsigned short* bph = Wth + (size_t)(cg0 * 16 + lane15) * H + quad * 8;
#pragma unroll
  for (int st = 0; st < 8; st++) {
    bf16x8 ah[4];
#pragma unroll
    for (int rg = 0; rg < 4; rg++)
      ah[rg] = *(const bf16x8*)(aph + rg * 16 * PITCH + st * 32);
#pragma unroll
    for (int cg = 0; cg < 2; cg++) {
      bf16x8 bhf = *(const bf16x8*)(bph + (size_t)cg * 16 * H + st * 32);
#pragma unroll
      for (int rg = 0; rg < 4; rg++)
        acc[rg][cg] = __builtin_amdgcn_mfma_f32_16x16x32_bf16(ah[rg], bhf, acc[rg][cg], 0, 0, 0);
    }
  }
  float bv[2];
#pragma unroll
  for (int cg = 0; cg < 2; cg++) bv[cg] = beta[(cg0 + cg) * 16 + lane15];
  // ---- coalesced h-gather (pre-barrier): wave reads one contiguous 256B run
  // per row; packed to bf16 pairs (16 regs). Loads drain under elbuf phase.
  int jcol = tid & 255, half = tid >> 8;
  const int* msrc = sSrc + half * 32;
  unsigned int hvp[16];
#pragma unroll
  for (int p = 0; p < 16; p++) {
    float f0 = h[(size_t)msrc[2 * p] * H + jcol];
    float f1 = h[(size_t)msrc[2 * p + 1] * H + jcol];
    hvp[p] = pack2bf(f0, f1);
  }
  __syncthreads();  // all waves done reading A; sAh becomes bf16 elbuf
#pragma unroll
  for (int rg = 0; rg < 4; rg++) {
#pragma unroll
    for (int r = 0; r < 4; r++) {
      int row = rg * 16 + quad * 4 + r;
#pragma unroll
      for (int cg = 0; cg < 2; cg++) {
        int j = (cg0 + cg) * 16 + lane15;
        sAh[row * PITCH + j] = f2bf(acc[rg][cg][r] + bv[cg]);
      }
    }
  }
  __syncthreads();
  // segment-reduced scatter: thread (half,jcol) walks its 32 dst-sorted rows.
  {
    const int* mdst = sDst + half * 32;
    float run = 0.f;
    int prev = mdst[0];
#pragma unroll
    for (int m = 0; m < 32; m++) {
      int d = mdst[m];
      unsigned int hp = hvp[m >> 1];
      unsigned short hu = (m & 1) ? (unsigned short)(hp >> 16) : (unsigned short)hp;
      float msg = fmaxf(bf2f(hu) + bf2f(sAh[(half * 32 + m) * PITCH + jcol]), 0.f);
      if (d != prev) {
        atomicAdd(&agg[(size_t)prev * H + jcol], run);
        run = 0.f;
        prev = d;
      }
      run += msg;
    }
    atomicAdd(&agg[(size_t)prev * H + jcol], run);
  }
}

// Node: z=h+agg; z1=relu(z@w1+b1); z2=z1@w2+b2; LN; h += relu(LN).
// Column-slice wave decomposition (wave owns 64 cols x all 64 rows).
// A single bf16 plane AND B single bf16 plane (hi only) on both GEMMs.
__global__ __launch_bounds__(256) void k_node_mfma(
    float* __restrict__ h, const float* __restrict__ agg,
    const unsigned short* __restrict__ w1Th, const float* __restrict__ b1,
    const unsigned short* __restrict__ w2Th, const float* __restrict__ b2,
    const float* __restrict__ lng, const float* __restrict__ lnb) {
  __shared__ __align__(16) unsigned short sAh[64 * PITCH];  // 33792 B
  __shared__ float sPartS[64][4];
  __shared__ float sPartQ[64][4];
  __shared__ float sMu[64];
  __shared__ float sRstd[64];
  int tid = threadIdx.x;
  int base = blockIdx.x * 64;
  const float4* h4 = (const float4*)(h + (size_t)base * H);
  const float4* a4 = (const float4*)(agg + (size_t)base * H);
#pragma unroll
  for (int it = 0; it < 16; it++) {  // all 64 rows (4096 float4)
    int vi = it * 256 + tid;
    int row = vi >> 6, c4 = (vi & 63) * 4;
    float4 hv = h4[vi], av = a4[vi];
    uint2 uh;
    uh.x = pack2bf(hv.x + av.x, hv.y + av.y);
    uh.y = pack2bf(hv.z + av.z, hv.w + av.w);
    *(uint2*)&sAh[row * PITCH + c4] = uh;
  }
  __syncthreads();
  int lane = tid & 63, wv = tid >> 6;
  int lane15 = lane & 15, quad = lane >> 4;
  int col0 = wv * 64;                 // wave's 64-col slice
  const unsigned short* aph = sAh + lane15 * PITCH + quad * 8;
  // ---- GEMM1: z1 = relu(z @ w1 + b1), acc[rg][cl]
  f32x4 acc[4][4];
#pragma unroll
  for (int i = 0; i < 4; i++)
#pragma unroll
    for (int c = 0; c < 4; c++) acc[i][c] = (f32x4){0.f, 0.f, 0.f, 0.f};
  {
    const unsigned short* bph = w1Th + (size_t)(col0 + lane15) * H + quad * 8;
#pragma unroll
    for (int st = 0; st < 8; st++) {
      bf16x8 ah[4];
#pragma unroll
      for (int rg = 0; rg < 4; rg++)
        ah[rg] = *(const bf16x8*)(aph + rg * 16 * PITCH + st * 32);
#pragma unroll
      for (int cl = 0; cl < 4; cl++) {
        bf16x8 bhf = *(const bf16x8*)(bph + (size_t)cl * 16 * H + st * 32);
#pragma unroll
        for (int rg = 0; rg < 4; rg++)
          acc[rg][cl] = __builtin_amdgcn_mfma_f32_16x16x32_bf16(ah[rg], bhf, acc[rg][cl], 0, 0, 0);
      }
    }
  }
  float b1v[4];
#pragma unroll
  for (int cl = 0; cl < 4; cl++) b1v[cl] = b1[col0 + cl * 16 + lane15];
  __syncthreads();  // all waves done reading z
#pragma unroll
  for (int rg = 0; rg < 4; rg++)
#pragma unroll
    for (int r = 0; r < 4; r++) {
      int row = rg * 16 + quad * 4 + r;
#pragma unroll
      for (int cl = 0; cl < 4; cl++) {
        int col = col0 + cl * 16 + lane15;
        sAh[row * PITCH + col] = f2bf(fmaxf(acc[rg][cl][r] + b1v[cl], 0.f));
      }
    }
  __syncthreads();
  // ---- GEMM2: z2 = z1 @ w2 + b2, acc2[rg][cl]
  f32x4 acc2[4][4];
#pragma unroll
  for (int i = 0; i < 4; i++)
#pragma unroll
    for (int c = 0; c < 4; c++) acc2[i][c] = (f32x4){0.f, 0.f, 0.f, 0.f};
  {
    const unsigned short* bph = w2Th + (size_t)(col0 + lane15) * H + quad * 8;
#pragma unroll
    for (int st = 0; st < 8; st++) {
      bf16x8 ah[4];
#pragma unroll
      for (int rg = 0; rg < 4; rg++)
        ah[rg] = *(const bf16x8*)(aph + rg * 16 * PITCH + st * 32);
#pragma unroll
      for (int cl = 0; cl < 4; cl++) {
        bf16x8 bhf = *(const bf16x8*)(bph + (size_t)cl * 16 * H + st * 32);
#pragma unroll
        for (int rg = 0; rg < 4; rg++)
          acc2[rg][cl] = __builtin_amdgcn_mfma_f32_16x16x32_bf16(ah[rg], bhf, acc2[rg][cl], 0, 0, 0);
      }
    }
  }
  float b2v[4], gv[4], bbv[4];
#pragma unroll
  for (int cl = 0; cl < 4; cl++) {
    int col = col0 + cl * 16 + lane15;
    b2v[cl] = b2[col]; gv[cl] = lng[col]; bbv[cl] = lnb[col];
  }
  // ---- LN partials: per row, reduce this wave's 64 cols
#pragma unroll
  for (int rg = 0; rg < 4; rg++)
#pragma unroll
    for (int r = 0; r < 4; r++) {
      int row = rg * 16 + quad * 4 + r;
      float s = 0.f, ss = 0.f;
#pragma unroll
      for (int cl = 0; cl < 4; cl++) {
        float z2 = acc2[rg][cl][r] + b2v[cl];
        s += z2;
        ss = fmaf(z2, z2, ss);
      }
      s += __shfl_xor(s, 1, 64); ss += __shfl_xor(ss, 1, 64);
      s += __shfl_xor(s, 2, 64); ss += __shfl_xor(ss, 2, 64);
      s += __shfl_xor(s, 4, 64); ss += __shfl_xor(ss, 4, 64);
      s += __shfl_xor(s, 8, 64); ss += __shfl_xor(ss, 8, 64);
      if (lane15 == 0) { sPartS[row][wv] = s; sPartQ[row][wv] = ss; }
    }
  __syncthreads();
  if (tid < 64) {
    float s = sPartS[tid][0] + sPartS[tid][1] + sPartS[tid][2] + sPartS[tid][3];
    float ss = sPartQ[tid][0] + sPartQ[tid][1] + sPartQ[tid][2] + sPartQ[tid][3];
    float mu = s * (1.f / H);
    float var = ss * (1.f / H) - mu * mu;
    sMu[tid] = mu;
    sRstd[tid] = rsqrtf(var + LN_EPS);
  }
  __syncthreads();
  // ---- apply LN + residual
#pragma unroll
  for (int rg = 0; rg < 4; rg++)
#pragma unroll
    for (int r = 0; r < 4; r++) {
      int row = rg * 16 + quad * 4 + r;
      float mu = sMu[row], rstd = sRstd[row];
      float* hr = h + (size_t)(base + row) * H;
#pragma unroll
      for (int cl = 0; cl < 4; cl++) {
        int col = col0 + cl * 16 + lane15;
        float z2 = acc2[rg][cl][r] + b2v[cl];
        float v = fmaf((z2 - mu) * rstd, gv[cl], bbv[cl]);
        hr[col] = hr[col] + fmaxf(v, 0.f);
      }
    }
}

// Partial mean-pool: block sums 64 rows into g[b][.] via atomics (fully parallel).
__global__ __launch_bounds__(256) void k_pool(
    const float* __restrict__ h, float* __restrict__ g, int n) {
  int tid = threadIdx.x;
  int row0 = blockIdx.x * 64;
  int b = row0 / n;                       // 64 | n, block never straddles graphs
  const float* hb = h + (size_t)row0 * H;
  float s0 = 0.f, s1 = 0.f, s2 = 0.f, s3 = 0.f;
  for (int i = 0; i < 64; i += 4) {
    s0 += hb[(size_t)(i + 0) * H + tid];
    s1 += hb[(size_t)(i + 1) * H + tid];
    s2 += hb[(size_t)(i + 2) * H + tid];
    s3 += hb[(size_t)(i + 3) * H + tid];
  }
  atomicAdd(&g[(size_t)b * H + tid], s0 + s1 + s2 + s3);
}

// Head MLP from pooled g. One block per graph.
__global__ __launch_bounds__(256) void k_head(
    const float* __restrict__ g,
    const float* __restrict__ w1, const float* __restrict__ b1,
    const float* __restrict__ w2, const float* __restrict__ b2,
    float* __restrict__ out, int n) {
  __shared__ float sG[H];
  __shared__ float sT[H];
  __shared__ float sR[4];
  int b = blockIdx.x, tid = threadIdx.x;
  sG[tid] = g[(size_t)b * H + tid] / (float)n;
  __syncthreads();
  float t = b1[tid];
  for (int k = 0; k < H; k++) t = fmaf(sG[k], w1[k * H + tid], t);
  sT[tid] = fmaxf(t, 0.f);
  __syncthreads();
  float p = sT[tid] * w2[tid];
#pragma unroll
  for (int off = 32; off > 0; off >>= 1) p += __shfl_xor(p, off, 64);
  if ((tid & 63) == 0) sR[tid >> 6] = p;
  __syncthreads();
  if (tid == 0) out[b] = sR[0] + sR[1] + sR[2] + sR[3] + b2[0];
}

// ---------- launcher ----------
extern "C" void kernel_launch(void* const* d_in, const int* in_sizes, int n_in,
                              void* d_out, int out_size, void* d_ws, size_t ws_size,
                              hipStream_t stream) {
  const float* x      = (const float*)d_in[0];
  const float* ea     = (const float*)d_in[1];
  const void*  ei     = d_in[2];
  const int*   a      = (const int*)d_in[3];
  const float* np_w   = (const float*)d_in[4];
  const float* np_b   = (const float*)d_in[5];
  const float* em_w1  = (const float*)d_in[6];
  const float* em_b1  = (const float*)d_in[7];
  const float* em_w2  = (const float*)d_in[8];
  const float* em_b2  = (const float*)d_in[9];
  const float* lin_w  = (const float*)d_in[10];
  const float* lin_b  = (const float*)d_in[11];
  const float* m_w1   = (const float*)d_in[12];
  const float* m_b1   = (const float*)d_in[13];
  const float* m_w2   = (const float*)d_in[14];
  const float* m_b2   = (const float*)d_in[15];
  const float* ln_g   = (const float*)d_in[16];
  const float* ln_b   = (const float*)d_in[17];
  const float* hd_w1  = (const float*)d_in[18];
  const float* hd_b1  = (const float*)d_in[19];
  const float* hd_w2  = (const float*)d_in[20];
  const float* hd_b2  = (const float*)d_in[21];

  int N = in_sizes[0] / 3;
  int E = in_sizes[1] / 4;
  int B = out_size;
  int n = N / B;

  // workspace layout (~82 MB)
  char* ws = (char*)d_ws;
  size_t off = 0;
  auto alloc = [&](size_t bytes) {
    char* p = ws + off;
    off += (bytes + 255) & ~(size_t)255;
    return p;
  };
  float* h    = (float*)alloc((size_t)N * H * 4);
  float* agg  = (float*)alloc((size_t)N * H * 4);
  unsigned short* wcTh = (unsigned short*)alloc((size_t)3 * H * H * 2);
  unsigned short* wcTl = (unsigned short*)alloc((size_t)3 * H * H * 2);
  unsigned short* w1Th = (unsigned short*)alloc((size_t)3 * H * H * 2);
  unsigned short* w1Tl = (unsigned short*)alloc((size_t)3 * H * H * 2);
  unsigned short* w2Th = (unsigned short*)alloc((size_t)3 * H * H * 2);
  unsigned short* w2Tl = (unsigned short*)alloc((size_t)3 * H * H * 2);
  float* beta  = (float*)alloc(3 * H * 4);
  int*   flag  = (int*)alloc(4);
  int*   hist  = (int*)alloc((size_t)N * 4);
  int*   curs  = (int*)alloc((size_t)N * 4);
  int*   srcS  = (int*)alloc((size_t)E * 4);
  int*   dstS  = (int*)alloc((size_t)E * 4);
  float* eaS   = (float*)alloc((size_t)E * 4 * 4);
  float* g     = (float*)alloc((size_t)B * H * 4);

  float* out = (float*)d_out;
  int ebl = (E + 255) / 256;

  k_detect<<<1, 64, 0, stream>>>((const int*)ei, flag);
  k_zero<<<(N + 1023) / 1024, 256, 0, stream>>>((float4*)hist, N / 4);
  k_hist<<<ebl, 256, 0, stream>>>(ei, flag, hist, E);
  k_scan<<<1, 256, 0, stream>>>(hist, curs, N);
  k_scatter<<<ebl, 256, 0, stream>>>(ei, flag, ea, curs, srcS, dstS, eaS, E);
  k_node_proj<<<N, 256, 0, stream>>>(x, a, np_w, np_b, h, N);
  k_wcomb<<<24, 256, 0, stream>>>(em_w2, lin_w, wcTh, wcTl);
  k_beta<<<3, 256, 0, stream>>>(lin_w, lin_b, em_b2, beta);
  k_transp<<<dim3(4, 4, 3), 256, 0, stream>>>(m_w1, w1Th, w1Tl);
  k_transp<<<dim3(4, 4, 3), 256, 0, stream>>>(m_w2, w2Th, w2Tl);

  int n4 = N * H / 4;
  for (int l = 0; l < 3; l++) {
    k_zero<<<(n4 + 255) / 256, 256, 0, stream>>>((float4*)agg, n4);
    k_edge_mfma<<<E / TE, 512, 0, stream>>>(eaS, em_w1, em_b1,
                                            wcTh + (size_t)l * H * H,
                                            beta + (size_t)l * H,
                                            h, agg, srcS, dstS);
    k_node_mfma<<<N / 64, 256, 0, stream>>>(h, agg,
                                            w1Th + (size_t)l * H * H,
                                            m_b1 + (size_t)l * H,
                                            w2Th + (size_t)l * H * H,
                                            m_b2 + (size_t)l * H,
                                            ln_g + (size_t)l * H, ln_b + (size_t)l * H);
  }
  int g4 = B * H / 4;
  k_zero<<<(g4 + 255) / 256, 256, 0, stream>>>((float4*)g, g4);
  k_pool<<<N / 64, 256, 0, stream>>>(h, g, n);
  k_head<<<B, 256, 0, stream>>>(g, hd_w1, hd_b1, hd_w2, hd_b2, out, n);
}

// Round 8
// 1008.453 us; speedup vs baseline: 1.0923x; 1.0174x over previous
//
#include <hip/hip_runtime.h>
#include <hip/hip_bf16.h>

#define H 256
#define LN_EPS 1e-5f
#define PITCH 264   // bf16 elements per LDS A-row (256 + 8 pad), 528 B
#define TE 64       // edges per tile (edge kernel)

typedef __attribute__((ext_vector_type(8))) short bf16x8;   // 8 bf16 = 4 VGPRs
typedef __attribute__((ext_vector_type(4))) float f32x4;    // MFMA 16x16 accum

// ---------- helpers ----------
__device__ __forceinline__ float bf2f(unsigned short u) {
  union { unsigned int i; float f; } v; v.i = ((unsigned int)u) << 16; return v.f;
}
__device__ __forceinline__ unsigned short f2bf(float f) {
  union { float f; unsigned int i; } v; v.f = f;
  unsigned int x = v.i;
  return (unsigned short)((x + 0x7fffu + ((x >> 16) & 1u)) >> 16);  // RNE
}
// packed pair: low 16 = a, high 16 = b (RNE, single v_cvt_pk_bf16_f32)
__device__ __forceinline__ unsigned int pack2bf(float a, float b) {
  __hip_bfloat162 t = __float22bfloat162_rn(make_float2(a, b));
  unsigned int u;
  __builtin_memcpy(&u, &t, 4);
  return u;
}
// single value via the same HW cvt (1 instruction, RNE)
__device__ __forceinline__ unsigned short f2bf1(float a) {
  return (unsigned short)pack2bf(a, a);
}
__device__ __forceinline__ void fsplit(float v, unsigned short& hi, unsigned short& lo) {
  hi = f2bf(v);
  lo = f2bf(v - bf2f(hi));
}

// fp32 register-tiled GEMM core (precompute only)
__device__ __forceinline__ void gemm_tile(const float* __restrict__ sA,
                                          const float* __restrict__ W,
                                          int lane_j, int rg, float acc[8][4]) {
#pragma unroll
  for (int mm = 0; mm < 8; mm++)
#pragma unroll
    for (int cc = 0; cc < 4; cc++) acc[mm][cc] = 0.f;
  for (int k = 0; k < H; k += 4) {
    float tvf[8][4];
#pragma unroll
    for (int mm = 0; mm < 8; mm++)
      *(float4*)&tvf[mm][0] = *(const float4*)&sA[(rg * 8 + mm) * H + k];
#pragma unroll
    for (int kk = 0; kk < 4; kk++) {
      const float* wr = W + (k + kk) * H + lane_j;
      float w0 = wr[0], w1 = wr[64], w2 = wr[128], w3 = wr[192];
#pragma unroll
      for (int mm = 0; mm < 8; mm++) {
        float av = tvf[mm][kk];
        acc[mm][0] = fmaf(av, w0, acc[mm][0]);
        acc[mm][1] = fmaf(av, w1, acc[mm][1]);
        acc[mm][2] = fmaf(av, w2, acc[mm][2]);
        acc[mm][3] = fmaf(av, w3, acc[mm][3]);
      }
    }
  }
}

// ---------- precompute kernels ----------

__global__ void k_detect(const int* __restrict__ ei, int* __restrict__ flag) {
  if (threadIdx.x == 0 && blockIdx.x == 0)
    *flag = (ei[1] == 0 && ei[3] == 0 && ei[5] == 0 && ei[7] == 0) ? 1 : 0;
}

__global__ __launch_bounds__(256) void k_zero(float4* __restrict__ p, int n4) {
  int i = blockIdx.x * 256 + threadIdx.x;
  if (i < n4) p[i] = make_float4(0.f, 0.f, 0.f, 0.f);
}

// dst histogram
__global__ __launch_bounds__(256) void k_hist(
    const void* __restrict__ ei, const int* __restrict__ flag64,
    int* __restrict__ hist, int E) {
  int e = blockIdx.x * 256 + threadIdx.x;
  if (e >= E) return;
  int d = (*flag64) ? (int)((const long long*)ei)[(size_t)E + e]
                    : ((const int*)ei)[(size_t)E + e];
  atomicAdd(&hist[d], 1);
}

// exclusive prefix sum over hist[N] -> cursor[N] (single block, 256 threads)
__global__ __launch_bounds__(256) void k_scan(
    const int* __restrict__ hist, int* __restrict__ cursor, int N) {
  __shared__ int part[256];
  int tid = threadIdx.x;
  int chunk = (N + 255) / 256;
  int s = 0;
  for (int i = 0; i < chunk; i++) {
    int idx = tid * chunk + i;
    if (idx < N) s += hist[idx];
  }
  part[tid] = s;
  __syncthreads();
  for (int off = 1; off < 256; off <<= 1) {
    int v = (tid >= off) ? part[tid - off] : 0;
    __syncthreads();
    part[tid] += v;
    __syncthreads();
  }
  int excl = (tid == 0) ? 0 : part[tid - 1];
  for (int i = 0; i < chunk; i++) {
    int idx = tid * chunk + i;
    if (idx < N) {
      cursor[idx] = excl;
      excl += hist[idx];
    }
  }
}

// scatter edges into dst-sorted order (src, dst, edge_attr)
__global__ __launch_bounds__(256) void k_scatter(
    const void* __restrict__ ei, const int* __restrict__ flag64,
    const float* __restrict__ ea, int* __restrict__ cursor,
    int* __restrict__ srcS, int* __restrict__ dstS, float* __restrict__ eaS, int E) {
  int e = blockIdx.x * 256 + threadIdx.x;
  if (e >= E) return;
  int is64 = *flag64;
  int s = is64 ? (int)((const long long*)ei)[e] : ((const int*)ei)[e];
  int d = is64 ? (int)((const long long*)ei)[(size_t)E + e]
               : ((const int*)ei)[(size_t)E + e];
  int p = atomicAdd(&cursor[d], 1);
  srcS[p] = s;
  dstS[p] = d;
  ((float4*)eaS)[p] = ((const float4*)ea)[e];
}

__global__ __launch_bounds__(256) void k_node_proj(
    const float* __restrict__ x, const int* __restrict__ a,
    const float* __restrict__ w, const float* __restrict__ b,
    float* __restrict__ h, int N) {
  int node = blockIdx.x;
  int j = threadIdx.x;
  float acc = b[j];
  acc = fmaf(x[node * 3 + 0], w[0 * H + j], acc);
  acc = fmaf(x[node * 3 + 1], w[1 * H + j], acc);
  acc = fmaf(x[node * 3 + 2], w[2 * H + j], acc);
  acc = fmaf((float)a[node], w[3 * H + j], acc);
  h[(size_t)node * H + j] = fmaxf(acc, 0.f);
}

// WtC[l][j][k] = (em_w2 @ lin_w[l])[k][j], hi/lo bf16 planes
__global__ __launch_bounds__(256, 2) void k_wcomb(
    const float* __restrict__ w2, const float* __restrict__ lin_w,
    unsigned short* __restrict__ wcTh, unsigned short* __restrict__ wcTl) {
  __shared__ __align__(16) float sA[32 * H];
  int l = blockIdx.x >> 3, tile = blockIdx.x & 7;
  int tid = threadIdx.x;
  const float4* src = (const float4*)(w2 + (size_t)tile * 32 * H);
#pragma unroll
  for (int it = 0; it < 8; it++) {
    int vi = it * 256 + tid;
    *(float4*)&sA[vi * 4] = src[vi];
  }
  __syncthreads();
  int lane_j = tid & 63, rg = tid >> 6;
  float acc[8][4];
  gemm_tile(sA, lin_w + (size_t)l * H * H, lane_j, rg, acc);
  unsigned short* oh = wcTh + (size_t)l * H * H;
  unsigned short* ol = wcTl + (size_t)l * H * H;
#pragma unroll
  for (int cc = 0; cc < 4; cc++) {
    int j = lane_j + 64 * cc;
#pragma unroll
    for (int mm = 0; mm < 8; mm++) {
      int k = tile * 32 + rg * 8 + mm;
      unsigned short hi, lo;
      fsplit(acc[mm][cc], hi, lo);
      oh[(size_t)j * H + k] = hi;
      ol[(size_t)j * H + k] = lo;
    }
  }
}

// beta[l] = em_b2 @ lin_w[l] + lin_b[l]
__global__ __launch_bounds__(256) void k_beta(
    const float* __restrict__ lin_w, const float* __restrict__ lin_b,
    const float* __restrict__ b2, float* __restrict__ beta) {
  int l = blockIdx.x, j = threadIdx.x;
  const float* W = lin_w + (size_t)l * H * H;
  float v = lin_b[l * H + j];
  for (int k = 0; k < H; k++) v = fmaf(b2[k], W[k * H + j], v);
  beta[l * H + j] = v;
}

// out_{h,l}[l][n][k] = bf16split(in[l][k][n])
__global__ __launch_bounds__(256) void k_transp(
    const float* __restrict__ in,
    unsigned short* __restrict__ outh, unsigned short* __restrict__ outl) {
  int l = blockIdx.z;
  int kb = blockIdx.x * 64, nb = blockIdx.y * 64;
  int tid = threadIdx.x;
  __shared__ float T[64][65];
  const float* src = in + (size_t)l * H * H;
#pragma unroll
  for (int it = 0; it < 16; it++) {
    int idx = it * 256 + tid;
    int kl = idx >> 6, nl = idx & 63;
    T[kl][nl] = src[(size_t)(kb + kl) * H + nb + nl];
  }
  __syncthreads();
  unsigned short* dh = outh + (size_t)l * H * H;
  unsigned short* dl = outl + (size_t)l * H * H;
#pragma unroll
  for (int it = 0; it < 8; it++) {
    int u = it * 256 + tid;
    int nl = u >> 5, k2 = (u & 31) * 2;
    unsigned short h0, l0, h1, l1;
    fsplit(T[k2][nl], h0, l0);
    fsplit(T[k2 + 1][nl], h1, l1);
    size_t o = (size_t)(nb + nl) * H + kb + k2;
    *(unsigned int*)&dh[o] = (unsigned int)h0 | ((unsigned int)h1 << 16);
    *(unsigned int*)&dl[o] = (unsigned int)l0 | ((unsigned int)l1 << 16);
  }
}

// ---------- per-layer MFMA kernels ----------

// Edge (dst-sorted), tile = TE(64) edges x 256 cols, 8 waves.
// A hi-plane, B hi-plane: e_l = A_hi * B_hi (64 MFMA/wave).
// R8 epilogue ordering: barrier -> elbuf write (acc DIES) -> issue coalesced
// hvp gather -> barrier -> scatter. acc and hvp never co-live, so peak regs
// fit the 85-cap of launch_bounds(512,6) without the R7 ~2-reg spill
// (WRITE_SIZE 81 MB -> expect ~48 MB). Single-inst v_cvt_pk bf16 converts.
__global__ __launch_bounds__(512, 6) void k_edge_mfma(
    const float* __restrict__ eaS,
    const float* __restrict__ w1, const float* __restrict__ b1,
    const unsigned short* __restrict__ Wth,
    const float* __restrict__ beta,
    const float* __restrict__ h, float* __restrict__ agg,
    const int* __restrict__ srcS, const int* __restrict__ dstS) {
  __shared__ __align__(16) unsigned short sAh[TE * PITCH];  // A-tile / bf16 elbuf
  __shared__ __align__(16) float sEA[TE * 4];
  __shared__ int sSrc[TE];
  __shared__ int sDst[TE];
  int tid = threadIdx.x;
  int base = blockIdx.x * TE;
  if (tid < TE) {
    sSrc[tid] = srcS[base + tid];
  } else if (tid < 2 * TE) {
    sDst[tid - TE] = dstS[base + tid - TE];
  } else if (tid < 3 * TE) {
    int t = tid - 2 * TE;
    ((float4*)sEA)[t] = ((const float4*)(eaS + (size_t)base * 4))[t];
  }
  __syncthreads();
  {  // t = relu(eaS @ w1 + b1) -> bf16 hi plane (col pair, 16 rows/thread)
    int j2 = (tid & 127) * 2;
    int r0 = (tid >> 7) * 16;
    float wv0[4], wv1[4];
#pragma unroll
    for (int q = 0; q < 4; q++) { wv0[q] = w1[q * H + j2]; wv1[q] = w1[q * H + j2 + 1]; }
    float bb0 = b1[j2], bb1 = b1[j2 + 1];
#pragma unroll
    for (int m = r0; m < r0 + 16; m++) {
      float t0 = bb0, t1 = bb1;
#pragma unroll
      for (int q = 0; q < 4; q++) {
        float eav = sEA[m * 4 + q];
        t0 = fmaf(eav, wv0[q], t0);
        t1 = fmaf(eav, wv1[q], t1);
      }
      *(unsigned int*)&sAh[m * PITCH + j2] = pack2bf(fmaxf(t0, 0.f), fmaxf(t1, 0.f));
    }
  }
  __syncthreads();
  int lane = tid & 63, wv = tid >> 6;           // wv in 0..7
  int lane15 = lane & 15, quad = lane >> 4;
  int cg0 = wv * 2;                             // wave's 2 col-groups (32 cols)
  f32x4 acc[4][2];
#pragma unroll
  for (int i = 0; i < 4; i++)
#pragma unroll
    for (int c = 0; c < 2; c++) acc[i][c] = (f32x4){0.f, 0.f, 0.f, 0.f};
  const unsigned short* aph = sAh + lane15 * PITCH + quad * 8;
  const unsigned short* bph = Wth + (size_t)(cg0 * 16 + lane15) * H + quad * 8;
#pragma unroll
  for (int st = 0; st < 8; st++) {
    bf16x8 ah[4];
#pragma unroll
    for (int rg = 0; rg < 4; rg++)
      ah[rg] = *(const bf16x8*)(aph + rg * 16 * PITCH + st * 32);
#pragma unroll
    for (int cg = 0; cg < 2; cg++) {
      bf16x8 bhf = *(const bf16x8*)(bph + (size_t)cg * 16 * H + st * 32);
#pragma unroll
      for (int rg = 0; rg < 4; rg++)
        acc[rg][cg] = __builtin_amdgcn_mfma_f32_16x16x32_bf16(ah[rg], bhf, acc[rg][cg], 0, 0, 0);
    }
  }
  float bv[2];
#pragma unroll
  for (int cg = 0; cg < 2; cg++) bv[cg] = beta[(cg0 + cg) * 16 + lane15];
  __syncthreads();  // all waves done reading A; sAh becomes bf16 elbuf
  // elbuf write first: acc dies here (never co-live with hvp below)
#pragma unroll
  for (int rg = 0; rg < 4; rg++) {
#pragma unroll
    for (int r = 0; r < 4; r++) {
      int row = rg * 16 + quad * 4 + r;
#pragma unroll
      for (int cg = 0; cg < 2; cg++) {
        int j = (cg0 + cg) * 16 + lane15;
        sAh[row * PITCH + j] = f2bf1(acc[rg][cg][r] + bv[cg]);
      }
    }
  }
  // coalesced h-gather: one contiguous 256B run per row per wave; packed bf16
  // pairs (16 regs). Loads drain under the barrier (other waves still writing).
  int jcol = tid & 255, half = tid >> 8;
  const int* msrc = sSrc + half * 32;
  unsigned int hvp[16];
#pragma unroll
  for (int p = 0; p < 16; p++) {
    float f0 = h[(size_t)msrc[2 * p] * H + jcol];
    float f1 = h[(size_t)msrc[2 * p + 1] * H + jcol];
    hvp[p] = pack2bf(f0, f1);
  }
  __syncthreads();
  // segment-reduced scatter: thread (half,jcol) walks its 32 dst-sorted rows.
  {
    const int* mdst = sDst + half * 32;
    float run = 0.f;
    int prev = mdst[0];
#pragma unroll
    for (int m = 0; m < 32; m++) {
      int d = mdst[m];
      unsigned int hp = hvp[m >> 1];
      unsigned short hu = (m & 1) ? (unsigned short)(hp >> 16) : (unsigned short)hp;
      float msg = fmaxf(bf2f(hu) + bf2f(sAh[(half * 32 + m) * PITCH + jcol]), 0.f);
      if (d != prev) {
        atomicAdd(&agg[(size_t)prev * H + jcol], run);
        run = 0.f;
        prev = d;
      }
      run += msg;
    }
    atomicAdd(&agg[(size_t)prev * H + jcol], run);
  }
}

// Node: z=h+agg; z1=relu(z@w1+b1); z2=z1@w2+b2; LN; h += relu(LN).
// R8: 32-row tiles (N/32 blocks). Old N/64 grid = 512 blocks on 256 CUs
// capped occupancy at 2 blk/CU x 4 waves = 25%. 1024 blocks -> 4 blk/CU = 50%.
// Wave owns 64 cols x 32 rows: acc[2][4]. LDS 17 KB.
__global__ __launch_bounds__(256) void k_node_mfma(
    float* __restrict__ h, const float* __restrict__ agg,
    const unsigned short* __restrict__ w1Th, const float* __restrict__ b1,
    const unsigned short* __restrict__ w2Th, const float* __restrict__ b2,
    const float* __restrict__ lng, const float* __restrict__ lnb) {
  __shared__ __align__(16) unsigned short sAh[32 * PITCH];  // 16896 B
  __shared__ float sPartS[32][4];
  __shared__ float sPartQ[32][4];
  __shared__ float sMu[32];
  __shared__ float sRstd[32];
  int tid = threadIdx.x;
  int base = blockIdx.x * 32;
  const float4* h4 = (const float4*)(h + (size_t)base * H);
  const float4* a4 = (const float4*)(agg + (size_t)base * H);
#pragma unroll
  for (int it = 0; it < 8; it++) {  // all 32 rows (2048 float4)
    int vi = it * 256 + tid;
    int row = vi >> 6, c4 = (vi & 63) * 4;
    float4 hv = h4[vi], av = a4[vi];
    uint2 uh;
    uh.x = pack2bf(hv.x + av.x, hv.y + av.y);
    uh.y = pack2bf(hv.z + av.z, hv.w + av.w);
    *(uint2*)&sAh[row * PITCH + c4] = uh;
  }
  __syncthreads();
  int lane = tid & 63, wv = tid >> 6;
  int lane15 = lane & 15, quad = lane >> 4;
  int col0 = wv * 64;                 // wave's 64-col slice
  const unsigned short* aph = sAh + lane15 * PITCH + quad * 8;
  // ---- GEMM1: z1 = relu(z @ w1 + b1), acc[rg][cl]
  f32x4 acc[2][4];
#pragma unroll
  for (int i = 0; i < 2; i++)
#pragma unroll
    for (int c = 0; c < 4; c++) acc[i][c] = (f32x4){0.f, 0.f, 0.f, 0.f};
  {
    const unsigned short* bph = w1Th + (size_t)(col0 + lane15) * H + quad * 8;
#pragma unroll
    for (int st = 0; st < 8; st++) {
      bf16x8 ah[2];
#pragma unroll
      for (int rg = 0; rg < 2; rg++)
        ah[rg] = *(const bf16x8*)(aph + rg * 16 * PITCH + st * 32);
#pragma unroll
      for (int cl = 0; cl < 4; cl++) {
        bf16x8 bhf = *(const bf16x8*)(bph + (size_t)cl * 16 * H + st * 32);
#pragma unroll
        for (int rg = 0; rg < 2; rg++)
          acc[rg][cl] = __builtin_amdgcn_mfma_f32_16x16x32_bf16(ah[rg], bhf, acc[rg][cl], 0, 0, 0);
      }
    }
  }
  float b1v[4];
#pragma unroll
  for (int cl = 0; cl < 4; cl++) b1v[cl] = b1[col0 + cl * 16 + lane15];
  __syncthreads();  // all waves done reading z
#pragma unroll
  for (int rg = 0; rg < 2; rg++)
#pragma unroll
    for (int r = 0; r < 4; r++) {
      int row = rg * 16 + quad * 4 + r;
#pragma unroll
      for (int cl = 0; cl < 4; cl++) {
        int col = col0 + cl * 16 + lane15;
        sAh[row * PITCH + col] = f2bf1(fmaxf(acc[rg][cl][r] + b1v[cl], 0.f));
      }
    }
  __syncthreads();
  // ---- GEMM2: z2 = z1 @ w2 + b2, acc2[rg][cl]
  f32x4 acc2[2][4];
#pragma unroll
  for (int i = 0; i < 2; i++)
#pragma unroll
    for (int c = 0; c < 4; c++) acc2[i][c] = (f32x4){0.f, 0.f, 0.f, 0.f};
  {
    const unsigned short* bph = w2Th + (size_t)(col0 + lane15) * H + quad * 8;
#pragma unroll
    for (int st = 0; st < 8; st++) {
      bf16x8 ah[2];
#pragma unroll
      for (int rg = 0; rg < 2; rg++)
        ah[rg] = *(const bf16x8*)(aph + rg * 16 * PITCH + st * 32);
#pragma unroll
      for (int cl = 0; cl < 4; cl++) {
        bf16x8 bhf = *(const bf16x8*)(bph + (size_t)cl * 16 * H + st * 32);
#pragma unroll
        for (int rg = 0; rg < 2; rg++)
          acc2[rg][cl] = __builtin_amdgcn_mfma_f32_16x16x32_bf16(ah[rg], bhf, acc2[rg][cl], 0, 0, 0);
      }
    }
  }
  float b2v[4], gv[4], bbv[4];
#pragma unroll
  for (int cl = 0; cl < 4; cl++) {
    int col = col0 + cl * 16 + lane15;
    b2v[cl] = b2[col]; gv[cl] = lng[col]; bbv[cl] = lnb[col];
  }
  // ---- LN partials: per row, reduce this wave's 64 cols
#pragma unroll
  for (int rg = 0; rg < 2; rg++)
#pragma unroll
    for (int r = 0; r < 4; r++) {
      int row = rg * 16 + quad * 4 + r;
      float s = 0.f, ss = 0.f;
#pragma unroll
      for (int cl = 0; cl < 4; cl++) {
        float z2 = acc2[rg][cl][r] + b2v[cl];
        s += z2;
        ss = fmaf(z2, z2, ss);
      }
      s += __shfl_xor(s, 1, 64); ss += __shfl_xor(ss, 1, 64);
      s += __shfl_xor(s, 2, 64); ss += __shfl_xor(ss, 2, 64);
      s += __shfl_xor(s, 4, 64); ss += __shfl_xor(ss, 4, 64);
      s += __shfl_xor(s, 8, 64); ss += __shfl_xor(ss, 8, 64);
      if (lane15 == 0) { sPartS[row][wv] = s; sPartQ[row][wv] = ss; }
    }
  __syncthreads();
  if (tid < 32) {
    float s = sPartS[tid][0] + sPartS[tid][1] + sPartS[tid][2] + sPartS[tid][3];
    float ss = sPartQ[tid][0] + sPartQ[tid][1] + sPartQ[tid][2] + sPartQ[tid][3];
    float mu = s * (1.f / H);
    float var = ss * (1.f / H) - mu * mu;
    sMu[tid] = mu;
    sRstd[tid] = rsqrtf(var + LN_EPS);
  }
  __syncthreads();
  // ---- apply LN + residual
#pragma unroll
  for (int rg = 0; rg < 2; rg++)
#pragma unroll
    for (int r = 0; r < 4; r++) {
      int row = rg * 16 + quad * 4 + r;
      float mu = sMu[row], rstd = sRstd[row];
      float* hr = h + (size_t)(base + row) * H;
#pragma unroll
      for (int cl = 0; cl < 4; cl++) {
        int col = col0 + cl * 16 + lane15;
        float z2 = acc2[rg][cl][r] + b2v[cl];
        float v = fmaf((z2 - mu) * rstd, gv[cl], bbv[cl]);
        hr[col] = hr[col] + fmaxf(v, 0.f);
      }
    }
}

// Partial mean-pool: block sums 64 rows into g[b][.] via atomics (fully parallel).
__global__ __launch_bounds__(256) void k_pool(
    const float* __restrict__ h, float* __restrict__ g, int n) {
  int tid = threadIdx.x;
  int row0 = blockIdx.x * 64;
  int b = row0 / n;                       // 64 | n, block never straddles graphs
  const float* hb = h + (size_t)row0 * H;
  float s0 = 0.f, s1 = 0.f, s2 = 0.f, s3 = 0.f;
  for (int i = 0; i < 64; i += 4) {
    s0 += hb[(size_t)(i + 0) * H + tid];
    s1 += hb[(size_t)(i + 1) * H + tid];
    s2 += hb[(size_t)(i + 2) * H + tid];
    s3 += hb[(size_t)(i + 3) * H + tid];
  }
  atomicAdd(&g[(size_t)b * H + tid], s0 + s1 + s2 + s3);
}

// Head MLP from pooled g. One block per graph.
__global__ __launch_bounds__(256) void k_head(
    const float* __restrict__ g,
    const float* __restrict__ w1, const float* __restrict__ b1,
    const float* __restrict__ w2, const float* __restrict__ b2,
    float* __restrict__ out, int n) {
  __shared__ float sG[H];
  __shared__ float sT[H];
  __shared__ float sR[4];
  int b = blockIdx.x, tid = threadIdx.x;
  sG[tid] = g[(size_t)b * H + tid] / (float)n;
  __syncthreads();
  float t = b1[tid];
  for (int k = 0; k < H; k++) t = fmaf(sG[k], w1[k * H + tid], t);
  sT[tid] = fmaxf(t, 0.f);
  __syncthreads();
  float p = sT[tid] * w2[tid];
#pragma unroll
  for (int off = 32; off > 0; off >>= 1) p += __shfl_xor(p, off, 64);
  if ((tid & 63) == 0) sR[tid >> 6] = p;
  __syncthreads();
  if (tid == 0) out[b] = sR[0] + sR[1] + sR[2] + sR[3] + b2[0];
}

// ---------- launcher ----------
extern "C" void kernel_launch(void* const* d_in, const int* in_sizes, int n_in,
                              void* d_out, int out_size, void* d_ws, size_t ws_size,
                              hipStream_t stream) {
  const float* x      = (const float*)d_in[0];
  const float* ea     = (const float*)d_in[1];
  const void*  ei     = d_in[2];
  const int*   a      = (const int*)d_in[3];
  const float* np_w   = (const float*)d_in[4];
  const float* np_b   = (const float*)d_in[5];
  const float* em_w1  = (const float*)d_in[6];
  const float* em_b1  = (const float*)d_in[7];
  const float* em_w2  = (const float*)d_in[8];
  const float* em_b2  = (const float*)d_in[9];
  const float* lin_w  = (const float*)d_in[10];
  const float* lin_b  = (const float*)d_in[11];
  const float* m_w1   = (const float*)d_in[12];
  const float* m_b1   = (const float*)d_in[13];
  const float* m_w2   = (const float*)d_in[14];
  const float* m_b2   = (const float*)d_in[15];
  const float* ln_g   = (const float*)d_in[16];
  const float* ln_b   = (const float*)d_in[17];
  const float* hd_w1  = (const float*)d_in[18];
  const float* hd_b1  = (const float*)d_in[19];
  const float* hd_w2  = (const float*)d_in[20];
  const float* hd_b2  = (const float*)d_in[21];

  int N = in_sizes[0] / 3;
  int E = in_sizes[1] / 4;
  int B = out_size;
  int n = N / B;

  // workspace layout (~82 MB)
  char* ws = (char*)d_ws;
  size_t off = 0;
  auto alloc = [&](size_t bytes) {
    char* p = ws + off;
    off += (bytes + 255) & ~(size_t)255;
    return p;
  };
  float* h    = (float*)alloc((size_t)N * H * 4);
  float* agg  = (float*)alloc((size_t)N * H * 4);
  unsigned short* wcTh = (unsigned short*)alloc((size_t)3 * H * H * 2);
  unsigned short* wcTl = (unsigned short*)alloc((size_t)3 * H * H * 2);
  unsigned short* w1Th = (unsigned short*)alloc((size_t)3 * H * H * 2);
  unsigned short* w1Tl = (unsigned short*)alloc((size_t)3 * H * H * 2);
  unsigned short* w2Th = (unsigned short*)alloc((size_t)3 * H * H * 2);
  unsigned short* w2Tl = (unsigned short*)alloc((size_t)3 * H * H * 2);
  float* beta  = (float*)alloc(3 * H * 4);
  int*   flag  = (int*)alloc(4);
  int*   hist  = (int*)alloc((size_t)N * 4);
  int*   curs  = (int*)alloc((size_t)N * 4);
  int*   srcS  = (int*)alloc((size_t)E * 4);
  int*   dstS  = (int*)alloc((size_t)E * 4);
  float* eaS   = (float*)alloc((size_t)E * 4 * 4);
  float* g     = (float*)alloc((size_t)B * H * 4);

  float* out = (float*)d_out;
  int ebl = (E + 255) / 256;

  k_detect<<<1, 64, 0, stream>>>((const int*)ei, flag);
  k_zero<<<(N + 1023) / 1024, 256, 0, stream>>>((float4*)hist, N / 4);
  k_hist<<<ebl, 256, 0, stream>>>(ei, flag, hist, E);
  k_scan<<<1, 256, 0, stream>>>(hist, curs, N);
  k_scatter<<<ebl, 256, 0, stream>>>(ei, flag, ea, curs, srcS, dstS, eaS, E);
  k_node_proj<<<N, 256, 0, stream>>>(x, a, np_w, np_b, h, N);
  k_wcomb<<<24, 256, 0, stream>>>(em_w2, lin_w, wcTh, wcTl);
  k_beta<<<3, 256, 0, stream>>>(lin_w, lin_b, em_b2, beta);
  k_transp<<<dim3(4, 4, 3), 256, 0, stream>>>(m_w1, w1Th, w1Tl);
  k_transp<<<dim3(4, 4, 3), 256, 0, stream>>>(m_w2, w2Th, w2Tl);

  int n4 = N * H / 4;
  for (int l = 0; l < 3; l++) {
    k_zero<<<(n4 + 255) / 256, 256, 0, stream>>>((float4*)agg, n4);
    k_edge_mfma<<<E / TE, 512, 0, stream>>>(eaS, em_w1, em_b1,
                                            wcTh + (size_t)l * H * H,
                                            beta + (size_t)l * H,
                                            h, agg, srcS, dstS);
    k_node_mfma<<<N / 32, 256, 0, stream>>>(h, agg,
                                            w1Th + (size_t)l * H * H,
                                            m_b1 + (size_t)l * H,
                                            w2Th + (size_t)l * H * H,
                                            m_b2 + (size_t)l * H,
                                            ln_g + (size_t)l * H, ln_b + (size_t)l * H);
  }
  int g4 = B * H / 4;
  k_zero<<<(g4 + 255) / 256, 256, 0, stream>>>((float4*)g, g4);
  k_pool<<<N / 64, 256, 0, stream>>>(h, g, n);
  k_head<<<B, 256, 0, stream>>>(g, hd_w1, hd_b1, hd_w2, hd_b2, out, n);
}

// Round 9
// 888.997 us; speedup vs baseline: 1.2390x; 1.1344x over previous
//
#include <hip/hip_runtime.h>
#include <hip/hip_bf16.h>

#define H 256
#define LN_EPS 1e-5f
#define PITCH 264   // bf16 elements per LDS A-row (256 + 8 pad), 528 B
#define TE 128      // edges per tile (edge kernel)

typedef __attribute__((ext_vector_type(8))) short bf16x8;   // 8 bf16 = 4 VGPRs
typedef __attribute__((ext_vector_type(4))) float f32x4;    // MFMA 16x16 accum

// ---------- helpers ----------
__device__ __forceinline__ float bf2f(unsigned short u) {
  union { unsigned int i; float f; } v; v.i = ((unsigned int)u) << 16; return v.f;
}
__device__ __forceinline__ unsigned short f2bf(float f) {
  union { float f; unsigned int i; } v; v.f = f;
  unsigned int x = v.i;
  return (unsigned short)((x + 0x7fffu + ((x >> 16) & 1u)) >> 16);  // RNE
}
// packed pair: low 16 = a, high 16 = b (RNE, single v_cvt_pk_bf16_f32)
__device__ __forceinline__ unsigned int pack2bf(float a, float b) {
  __hip_bfloat162 t = __float22bfloat162_rn(make_float2(a, b));
  unsigned int u;
  __builtin_memcpy(&u, &t, 4);
  return u;
}
// single value via the same HW cvt (1 instruction, RNE)
__device__ __forceinline__ unsigned short f2bf1(float a) {
  return (unsigned short)pack2bf(a, a);
}
__device__ __forceinline__ void fsplit(float v, unsigned short& hi, unsigned short& lo) {
  hi = f2bf(v);
  lo = f2bf(v - bf2f(hi));
}

// fp32 register-tiled GEMM core (precompute only)
__device__ __forceinline__ void gemm_tile(const float* __restrict__ sA,
                                          const float* __restrict__ W,
                                          int lane_j, int rg, float acc[8][4]) {
#pragma unroll
  for (int mm = 0; mm < 8; mm++)
#pragma unroll
    for (int cc = 0; cc < 4; cc++) acc[mm][cc] = 0.f;
  for (int k = 0; k < H; k += 4) {
    float tvf[8][4];
#pragma unroll
    for (int mm = 0; mm < 8; mm++)
      *(float4*)&tvf[mm][0] = *(const float4*)&sA[(rg * 8 + mm) * H + k];
#pragma unroll
    for (int kk = 0; kk < 4; kk++) {
      const float* wr = W + (k + kk) * H + lane_j;
      float w0 = wr[0], w1 = wr[64], w2 = wr[128], w3 = wr[192];
#pragma unroll
      for (int mm = 0; mm < 8; mm++) {
        float av = tvf[mm][kk];
        acc[mm][0] = fmaf(av, w0, acc[mm][0]);
        acc[mm][1] = fmaf(av, w1, acc[mm][1]);
        acc[mm][2] = fmaf(av, w2, acc[mm][2]);
        acc[mm][3] = fmaf(av, w3, acc[mm][3]);
      }
    }
  }
}

// ---------- precompute kernels ----------

__global__ void k_detect(const int* __restrict__ ei, int* __restrict__ flag) {
  if (threadIdx.x == 0 && blockIdx.x == 0)
    *flag = (ei[1] == 0 && ei[3] == 0 && ei[5] == 0 && ei[7] == 0) ? 1 : 0;
}

__global__ __launch_bounds__(256) void k_zero(float4* __restrict__ p, int n4) {
  int i = blockIdx.x * 256 + threadIdx.x;
  if (i < n4) p[i] = make_float4(0.f, 0.f, 0.f, 0.f);
}

// dst histogram
__global__ __launch_bounds__(256) void k_hist(
    const void* __restrict__ ei, const int* __restrict__ flag64,
    int* __restrict__ hist, int E) {
  int e = blockIdx.x * 256 + threadIdx.x;
  if (e >= E) return;
  int d = (*flag64) ? (int)((const long long*)ei)[(size_t)E + e]
                    : ((const int*)ei)[(size_t)E + e];
  atomicAdd(&hist[d], 1);
}

// exclusive prefix sum over hist[N] -> cursor[N] (single block, 256 threads)
__global__ __launch_bounds__(256) void k_scan(
    const int* __restrict__ hist, int* __restrict__ cursor, int N) {
  __shared__ int part[256];
  int tid = threadIdx.x;
  int chunk = (N + 255) / 256;
  int s = 0;
  for (int i = 0; i < chunk; i++) {
    int idx = tid * chunk + i;
    if (idx < N) s += hist[idx];
  }
  part[tid] = s;
  __syncthreads();
  for (int off = 1; off < 256; off <<= 1) {
    int v = (tid >= off) ? part[tid - off] : 0;
    __syncthreads();
    part[tid] += v;
    __syncthreads();
  }
  int excl = (tid == 0) ? 0 : part[tid - 1];
  for (int i = 0; i < chunk; i++) {
    int idx = tid * chunk + i;
    if (idx < N) {
      cursor[idx] = excl;
      excl += hist[idx];
    }
  }
}

// scatter edges into dst-sorted order (src, dst, edge_attr)
__global__ __launch_bounds__(256) void k_scatter(
    const void* __restrict__ ei, const int* __restrict__ flag64,
    const float* __restrict__ ea, int* __restrict__ cursor,
    int* __restrict__ srcS, int* __restrict__ dstS, float* __restrict__ eaS, int E) {
  int e = blockIdx.x * 256 + threadIdx.x;
  if (e >= E) return;
  int is64 = *flag64;
  int s = is64 ? (int)((const long long*)ei)[e] : ((const int*)ei)[e];
  int d = is64 ? (int)((const long long*)ei)[(size_t)E + e]
               : ((const int*)ei)[(size_t)E + e];
  int p = atomicAdd(&cursor[d], 1);
  srcS[p] = s;
  dstS[p] = d;
  ((float4*)eaS)[p] = ((const float4*)ea)[e];
}

__global__ __launch_bounds__(256) void k_node_proj(
    const float* __restrict__ x, const int* __restrict__ a,
    const float* __restrict__ w, const float* __restrict__ b,
    float* __restrict__ h, int N) {
  int node = blockIdx.x;
  int j = threadIdx.x;
  float acc = b[j];
  acc = fmaf(x[node * 3 + 0], w[0 * H + j], acc);
  acc = fmaf(x[node * 3 + 1], w[1 * H + j], acc);
  acc = fmaf(x[node * 3 + 2], w[2 * H + j], acc);
  acc = fmaf((float)a[node], w[3 * H + j], acc);
  h[(size_t)node * H + j] = fmaxf(acc, 0.f);
}

// WtC[l][j][k] = (em_w2 @ lin_w[l])[k][j], hi/lo bf16 planes
__global__ __launch_bounds__(256, 2) void k_wcomb(
    const float* __restrict__ w2, const float* __restrict__ lin_w,
    unsigned short* __restrict__ wcTh, unsigned short* __restrict__ wcTl) {
  __shared__ __align__(16) float sA[32 * H];
  int l = blockIdx.x >> 3, tile = blockIdx.x & 7;
  int tid = threadIdx.x;
  const float4* src = (const float4*)(w2 + (size_t)tile * 32 * H);
#pragma unroll
  for (int it = 0; it < 8; it++) {
    int vi = it * 256 + tid;
    *(float4*)&sA[vi * 4] = src[vi];
  }
  __syncthreads();
  int lane_j = tid & 63, rg = tid >> 6;
  float acc[8][4];
  gemm_tile(sA, lin_w + (size_t)l * H * H, lane_j, rg, acc);
  unsigned short* oh = wcTh + (size_t)l * H * H;
  unsigned short* ol = wcTl + (size_t)l * H * H;
#pragma unroll
  for (int cc = 0; cc < 4; cc++) {
    int j = lane_j + 64 * cc;
#pragma unroll
    for (int mm = 0; mm < 8; mm++) {
      int k = tile * 32 + rg * 8 + mm;
      unsigned short hi, lo;
      fsplit(acc[mm][cc], hi, lo);
      oh[(size_t)j * H + k] = hi;
      ol[(size_t)j * H + k] = lo;
    }
  }
}

// beta[l] = em_b2 @ lin_w[l] + lin_b[l]
__global__ __launch_bounds__(256) void k_beta(
    const float* __restrict__ lin_w, const float* __restrict__ lin_b,
    const float* __restrict__ b2, float* __restrict__ beta) {
  int l = blockIdx.x, j = threadIdx.x;
  const float* W = lin_w + (size_t)l * H * H;
  float v = lin_b[l * H + j];
  for (int k = 0; k < H; k++) v = fmaf(b2[k], W[k * H + j], v);
  beta[l * H + j] = v;
}

// out_{h,l}[l][n][k] = bf16split(in[l][k][n])
__global__ __launch_bounds__(256) void k_transp(
    const float* __restrict__ in,
    unsigned short* __restrict__ outh, unsigned short* __restrict__ outl) {
  int l = blockIdx.z;
  int kb = blockIdx.x * 64, nb = blockIdx.y * 64;
  int tid = threadIdx.x;
  __shared__ float T[64][65];
  const float* src = in + (size_t)l * H * H;
#pragma unroll
  for (int it = 0; it < 16; it++) {
    int idx = it * 256 + tid;
    int kl = idx >> 6, nl = idx & 63;
    T[kl][nl] = src[(size_t)(kb + kl) * H + nb + nl];
  }
  __syncthreads();
  unsigned short* dh = outh + (size_t)l * H * H;
  unsigned short* dl = outl + (size_t)l * H * H;
#pragma unroll
  for (int it = 0; it < 8; it++) {
    int u = it * 256 + tid;
    int nl = u >> 5, k2 = (u & 31) * 2;
    unsigned short h0, l0, h1, l1;
    fsplit(T[k2][nl], h0, l0);
    fsplit(T[k2 + 1][nl], h1, l1);
    size_t o = (size_t)(nb + nl) * H + kb + k2;
    *(unsigned int*)&dh[o] = (unsigned int)h0 | ((unsigned int)h1 << 16);
    *(unsigned int*)&dl[o] = (unsigned int)l0 | ((unsigned int)l1 << 16);
  }
}

// ---------- per-layer MFMA kernels ----------

// Edge (dst-sorted), tile = TE(128) edges x 256 cols, 16 waves x 1024 thr.
// R9 geometry: wave wv owns ONE col-group (16 cols) x ALL 8 row-groups ->
// acc[8] = 32 regs, only ONE ah + ONE bhf live at a time (no fragment
// arrays). Peak live ~55 regs -> fits the 64-reg cap of launch_bounds
// (1024,8) -> 2 blocks/CU = 32 waves/CU (100%), vs 3x8=24 at TE=64.
// B-stream per edge halves (each B fragment feeds 8 MFMAs). A-LDS reads
// double (no cg reuse) but LDS port is at ~7% - irrelevant.
// History: (512,8)+fat kernel = R2 spill storm. Watch WRITE_SIZE: if it
// balloons above ~60 MB the 64-cap spilled -> revert to R8 geometry.
__global__ __launch_bounds__(1024, 8) void k_edge_mfma(
    const float* __restrict__ eaS,
    const float* __restrict__ w1, const float* __restrict__ b1,
    const unsigned short* __restrict__ Wth,
    const float* __restrict__ beta,
    const float* __restrict__ h, float* __restrict__ agg,
    const int* __restrict__ srcS, const int* __restrict__ dstS) {
  __shared__ __align__(16) unsigned short sAh[TE * PITCH];  // 67584 B, A-tile / bf16 elbuf
  __shared__ __align__(16) float sEA[TE * 4];               // 2048 B
  __shared__ int sSrc[TE];
  __shared__ int sDst[TE];
  int tid = threadIdx.x;
  int base = blockIdx.x * TE;
  if (tid < TE) {
    sSrc[tid] = srcS[base + tid];
  } else if (tid < 2 * TE) {
    sDst[tid - TE] = dstS[base + tid - TE];
  } else if (tid < 3 * TE) {
    int t = tid - 2 * TE;
    ((float4*)sEA)[t] = ((const float4*)(eaS + (size_t)base * 4))[t];
  }
  __syncthreads();
  {  // t = relu(eaS @ w1 + b1) -> bf16 hi plane (col pair, 16 rows/thread)
    int j2 = (tid & 127) * 2;
    int r0 = (tid >> 7) * 16;          // 8 groups x 16 rows = 128 rows
    float wv0[4], wv1[4];
#pragma unroll
    for (int q = 0; q < 4; q++) { wv0[q] = w1[q * H + j2]; wv1[q] = w1[q * H + j2 + 1]; }
    float bb0 = b1[j2], bb1 = b1[j2 + 1];
#pragma unroll
    for (int m = r0; m < r0 + 16; m++) {
      float t0 = bb0, t1 = bb1;
#pragma unroll
      for (int q = 0; q < 4; q++) {
        float eav = sEA[m * 4 + q];
        t0 = fmaf(eav, wv0[q], t0);
        t1 = fmaf(eav, wv1[q], t1);
      }
      *(unsigned int*)&sAh[m * PITCH + j2] = pack2bf(fmaxf(t0, 0.f), fmaxf(t1, 0.f));
    }
  }
  __syncthreads();
  int lane = tid & 63, wv = tid >> 6;           // wv in 0..15 = col-group
  int lane15 = lane & 15, quad = lane >> 4;
  f32x4 acc[8];
#pragma unroll
  for (int i = 0; i < 8; i++) acc[i] = (f32x4){0.f, 0.f, 0.f, 0.f};
  const unsigned short* aph = sAh + lane15 * PITCH + quad * 8;
  const unsigned short* bph = Wth + (size_t)(wv * 16 + lane15) * H + quad * 8;
#pragma unroll
  for (int st = 0; st < 8; st++) {
    bf16x8 bhf = *(const bf16x8*)(bph + st * 32);
#pragma unroll
    for (int rg = 0; rg < 8; rg++) {
      bf16x8 ah = *(const bf16x8*)(aph + rg * 16 * PITCH + st * 32);
      acc[rg] = __builtin_amdgcn_mfma_f32_16x16x32_bf16(ah, bhf, acc[rg], 0, 0, 0);
    }
  }
  float bv = beta[wv * 16 + lane15];
  __syncthreads();  // all waves done reading A; sAh becomes bf16 elbuf
  // elbuf write first: acc dies here (never co-live with hvp below)
#pragma unroll
  for (int rg = 0; rg < 8; rg++) {
#pragma unroll
    for (int r = 0; r < 4; r++) {
      int row = rg * 16 + quad * 4 + r;
      sAh[row * PITCH + wv * 16 + lane15] = f2bf1(acc[rg][r] + bv);
    }
  }
  // coalesced h-gather: one contiguous 256B run per row per wave; packed bf16
  // pairs (16 regs). Loads drain under the barrier (other waves still writing).
  int jcol = tid & 255, quarter = tid >> 8;
  const int* msrc = sSrc + quarter * 32;
  unsigned int hvp[16];
#pragma unroll
  for (int p = 0; p < 16; p++) {
    float f0 = h[(size_t)msrc[2 * p] * H + jcol];
    float f1 = h[(size_t)msrc[2 * p + 1] * H + jcol];
    hvp[p] = pack2bf(f0, f1);
  }
  __syncthreads();
  // segment-reduced scatter: thread (quarter,jcol) walks its 32 dst-sorted rows.
  {
    const int* mdst = sDst + quarter * 32;
    float run = 0.f;
    int prev = mdst[0];
#pragma unroll
    for (int m = 0; m < 32; m++) {
      int d = mdst[m];
      unsigned int hp = hvp[m >> 1];
      unsigned short hu = (m & 1) ? (unsigned short)(hp >> 16) : (unsigned short)hp;
      float msg = fmaxf(bf2f(hu) + bf2f(sAh[(quarter * 32 + m) * PITCH + jcol]), 0.f);
      if (d != prev) {
        atomicAdd(&agg[(size_t)prev * H + jcol], run);
        run = 0.f;
        prev = d;
      }
      run += msg;
    }
    atomicAdd(&agg[(size_t)prev * H + jcol], run);
  }
}

// Node: z=h+agg; z1=relu(z@w1+b1); z2=z1@w2+b2; LN; h += relu(LN).
// 32-row tiles (N/32 = 1024 blocks -> 4 blk/CU x 4 waves = 50% occ ceiling).
// Wave owns 64 cols x 32 rows: acc[2][4]. LDS 17 KB.
__global__ __launch_bounds__(256) void k_node_mfma(
    float* __restrict__ h, const float* __restrict__ agg,
    const unsigned short* __restrict__ w1Th, const float* __restrict__ b1,
    const unsigned short* __restrict__ w2Th, const float* __restrict__ b2,
    const float* __restrict__ lng, const float* __restrict__ lnb) {
  __shared__ __align__(16) unsigned short sAh[32 * PITCH];  // 16896 B
  __shared__ float sPartS[32][4];
  __shared__ float sPartQ[32][4];
  __shared__ float sMu[32];
  __shared__ float sRstd[32];
  int tid = threadIdx.x;
  int base = blockIdx.x * 32;
  const float4* h4 = (const float4*)(h + (size_t)base * H);
  const float4* a4 = (const float4*)(agg + (size_t)base * H);
#pragma unroll
  for (int it = 0; it < 8; it++) {  // all 32 rows (2048 float4)
    int vi = it * 256 + tid;
    int row = vi >> 6, c4 = (vi & 63) * 4;
    float4 hv = h4[vi], av = a4[vi];
    uint2 uh;
    uh.x = pack2bf(hv.x + av.x, hv.y + av.y);
    uh.y = pack2bf(hv.z + av.z, hv.w + av.w);
    *(uint2*)&sAh[row * PITCH + c4] = uh;
  }
  __syncthreads();
  int lane = tid & 63, wv = tid >> 6;
  int lane15 = lane & 15, quad = lane >> 4;
  int col0 = wv * 64;                 // wave's 64-col slice
  const unsigned short* aph = sAh + lane15 * PITCH + quad * 8;
  // ---- GEMM1: z1 = relu(z @ w1 + b1), acc[rg][cl]
  f32x4 acc[2][4];
#pragma unroll
  for (int i = 0; i < 2; i++)
#pragma unroll
    for (int c = 0; c < 4; c++) acc[i][c] = (f32x4){0.f, 0.f, 0.f, 0.f};
  {
    const unsigned short* bph = w1Th + (size_t)(col0 + lane15) * H + quad * 8;
#pragma unroll
    for (int st = 0; st < 8; st++) {
      bf16x8 ah[2];
#pragma unroll
      for (int rg = 0; rg < 2; rg++)
        ah[rg] = *(const bf16x8*)(aph + rg * 16 * PITCH + st * 32);
#pragma unroll
      for (int cl = 0; cl < 4; cl++) {
        bf16x8 bhf = *(const bf16x8*)(bph + (size_t)cl * 16 * H + st * 32);
#pragma unroll
        for (int rg = 0; rg < 2; rg++)
          acc[rg][cl] = __builtin_amdgcn_mfma_f32_16x16x32_bf16(ah[rg], bhf, acc[rg][cl], 0, 0, 0);
      }
    }
  }
  float b1v[4];
#pragma unroll
  for (int cl = 0; cl < 4; cl++) b1v[cl] = b1[col0 + cl * 16 + lane15];
  __syncthreads();  // all waves done reading z
#pragma unroll
  for (int rg = 0; rg < 2; rg++)
#pragma unroll
    for (int r = 0; r < 4; r++) {
      int row = rg * 16 + quad * 4 + r;
#pragma unroll
      for (int cl = 0; cl < 4; cl++) {
        int col = col0 + cl * 16 + lane15;
        sAh[row * PITCH + col] = f2bf1(fmaxf(acc[rg][cl][r] + b1v[cl], 0.f));
      }
    }
  __syncthreads();
  // ---- GEMM2: z2 = z1 @ w2 + b2, acc2[rg][cl]
  f32x4 acc2[2][4];
#pragma unroll
  for (int i = 0; i < 2; i++)
#pragma unroll
    for (int c = 0; c < 4; c++) acc2[i][c] = (f32x4){0.f, 0.f, 0.f, 0.f};
  {
    const unsigned short* bph = w2Th + (size_t)(col0 + lane15) * H + quad * 8;
#pragma unroll
    for (int st = 0; st < 8; st++) {
      bf16x8 ah[2];
#pragma unroll
      for (int rg = 0; rg < 2; rg++)
        ah[rg] = *(const bf16x8*)(aph + rg * 16 * PITCH + st * 32);
#pragma unroll
      for (int cl = 0; cl < 4; cl++) {
        bf16x8 bhf = *(const bf16x8*)(bph + (size_t)cl * 16 * H + st * 32);
#pragma unroll
        for (int rg = 0; rg < 2; rg++)
          acc2[rg][cl] = __builtin_amdgcn_mfma_f32_16x16x32_bf16(ah[rg], bhf, acc2[rg][cl], 0, 0, 0);
      }
    }
  }
  float b2v[4], gv[4], bbv[4];
#pragma unroll
  for (int cl = 0; cl < 4; cl++) {
    int col = col0 + cl * 16 + lane15;
    b2v[cl] = b2[col]; gv[cl] = lng[col]; bbv[cl] = lnb[col];
  }
  // ---- LN partials: per row, reduce this wave's 64 cols
#pragma unroll
  for (int rg = 0; rg < 2; rg++)
#pragma unroll
    for (int r = 0; r < 4; r++) {
      int row = rg * 16 + quad * 4 + r;
      float s = 0.f, ss = 0.f;
#pragma unroll
      for (int cl = 0; cl < 4; cl++) {
        float z2 = acc2[rg][cl][r] + b2v[cl];
        s += z2;
        ss = fmaf(z2, z2, ss);
      }
      s += __shfl_xor(s, 1, 64); ss += __shfl_xor(ss, 1, 64);
      s += __shfl_xor(s, 2, 64); ss += __shfl_xor(ss, 2, 64);
      s += __shfl_xor(s, 4, 64); ss += __shfl_xor(ss, 4, 64);
      s += __shfl_xor(s, 8, 64); ss += __shfl_xor(ss, 8, 64);
      if (lane15 == 0) { sPartS[row][wv] = s; sPartQ[row][wv] = ss; }
    }
  __syncthreads();
  if (tid < 32) {
    float s = sPartS[tid][0] + sPartS[tid][1] + sPartS[tid][2] + sPartS[tid][3];
    float ss = sPartQ[tid][0] + sPartQ[tid][1] + sPartQ[tid][2] + sPartQ[tid][3];
    float mu = s * (1.f / H);
    float var = ss * (1.f / H) - mu * mu;
    sMu[tid] = mu;
    sRstd[tid] = rsqrtf(var + LN_EPS);
  }
  __syncthreads();
  // ---- apply LN + residual
#pragma unroll
  for (int rg = 0; rg < 2; rg++)
#pragma unroll
    for (int r = 0; r < 4; r++) {
      int row = rg * 16 + quad * 4 + r;
      float mu = sMu[row], rstd = sRstd[row];
      float* hr = h + (size_t)(base + row) * H;
#pragma unroll
      for (int cl = 0; cl < 4; cl++) {
        int col = col0 + cl * 16 + lane15;
        float z2 = acc2[rg][cl][r] + b2v[cl];
        float v = fmaf((z2 - mu) * rstd, gv[cl], bbv[cl]);
        hr[col] = hr[col] + fmaxf(v, 0.f);
      }
    }
}

// Partial mean-pool: block sums 64 rows into g[b][.] via atomics (fully parallel).
__global__ __launch_bounds__(256) void k_pool(
    const float* __restrict__ h, float* __restrict__ g, int n) {
  int tid = threadIdx.x;
  int row0 = blockIdx.x * 64;
  int b = row0 / n;                       // 64 | n, block never straddles graphs
  const float* hb = h + (size_t)row0 * H;
  float s0 = 0.f, s1 = 0.f, s2 = 0.f, s3 = 0.f;
  for (int i = 0; i < 64; i += 4) {
    s0 += hb[(size_t)(i + 0) * H + tid];
    s1 += hb[(size_t)(i + 1) * H + tid];
    s2 += hb[(size_t)(i + 2) * H + tid];
    s3 += hb[(size_t)(i + 3) * H + tid];
  }
  atomicAdd(&g[(size_t)b * H + tid], s0 + s1 + s2 + s3);
}

// Head MLP from pooled g. One block per graph.
__global__ __launch_bounds__(256) void k_head(
    const float* __restrict__ g,
    const float* __restrict__ w1, const float* __restrict__ b1,
    const float* __restrict__ w2, const float* __restrict__ b2,
    float* __restrict__ out, int n) {
  __shared__ float sG[H];
  __shared__ float sT[H];
  __shared__ float sR[4];
  int b = blockIdx.x, tid = threadIdx.x;
  sG[tid] = g[(size_t)b * H + tid] / (float)n;
  __syncthreads();
  float t = b1[tid];
  for (int k = 0; k < H; k++) t = fmaf(sG[k], w1[k * H + tid], t);
  sT[tid] = fmaxf(t, 0.f);
  __syncthreads();
  float p = sT[tid] * w2[tid];
#pragma unroll
  for (int off = 32; off > 0; off >>= 1) p += __shfl_xor(p, off, 64);
  if ((tid & 63) == 0) sR[tid >> 6] = p;
  __syncthreads();
  if (tid == 0) out[b] = sR[0] + sR[1] + sR[2] + sR[3] + b2[0];
}

// ---------- launcher ----------
extern "C" void kernel_launch(void* const* d_in, const int* in_sizes, int n_in,
                              void* d_out, int out_size, void* d_ws, size_t ws_size,
                              hipStream_t stream) {
  const float* x      = (const float*)d_in[0];
  const float* ea     = (const float*)d_in[1];
  const void*  ei     = d_in[2];
  const int*   a      = (const int*)d_in[3];
  const float* np_w   = (const float*)d_in[4];
  const float* np_b   = (const float*)d_in[5];
  const float* em_w1  = (const float*)d_in[6];
  const float* em_b1  = (const float*)d_in[7];
  const float* em_w2  = (const float*)d_in[8];
  const float* em_b2  = (const float*)d_in[9];
  const float* lin_w  = (const float*)d_in[10];
  const float* lin_b  = (const float*)d_in[11];
  const float* m_w1   = (const float*)d_in[12];
  const float* m_b1   = (const float*)d_in[13];
  const float* m_w2   = (const float*)d_in[14];
  const float* m_b2   = (const float*)d_in[15];
  const float* ln_g   = (const float*)d_in[16];
  const float* ln_b   = (const float*)d_in[17];
  const float* hd_w1  = (const float*)d_in[18];
  const float* hd_b1  = (const float*)d_in[19];
  const float* hd_w2  = (const float*)d_in[20];
  const float* hd_b2  = (const float*)d_in[21];

  int N = in_sizes[0] / 3;
  int E = in_sizes[1] / 4;
  int B = out_size;
  int n = N / B;

  // workspace layout (~82 MB)
  char* ws = (char*)d_ws;
  size_t off = 0;
  auto alloc = [&](size_t bytes) {
    char* p = ws + off;
    off += (bytes + 255) & ~(size_t)255;
    return p;
  };
  float* h    = (float*)alloc((size_t)N * H * 4);
  float* agg  = (float*)alloc((size_t)N * H * 4);
  unsigned short* wcTh = (unsigned short*)alloc((size_t)3 * H * H * 2);
  unsigned short* wcTl = (unsigned short*)alloc((size_t)3 * H * H * 2);
  unsigned short* w1Th = (unsigned short*)alloc((size_t)3 * H * H * 2);
  unsigned short* w1Tl = (unsigned short*)alloc((size_t)3 * H * H * 2);
  unsigned short* w2Th = (unsigned short*)alloc((size_t)3 * H * H * 2);
  unsigned short* w2Tl = (unsigned short*)alloc((size_t)3 * H * H * 2);
  float* beta  = (float*)alloc(3 * H * 4);
  int*   flag  = (int*)alloc(4);
  int*   hist  = (int*)alloc((size_t)N * 4);
  int*   curs  = (int*)alloc((size_t)N * 4);
  int*   srcS  = (int*)alloc((size_t)E * 4);
  int*   dstS  = (int*)alloc((size_t)E * 4);
  float* eaS   = (float*)alloc((size_t)E * 4 * 4);
  float* g     = (float*)alloc((size_t)B * H * 4);

  float* out = (float*)d_out;
  int ebl = (E + 255) / 256;

  k_detect<<<1, 64, 0, stream>>>((const int*)ei, flag);
  k_zero<<<(N + 1023) / 1024, 256, 0, stream>>>((float4*)hist, N / 4);
  k_hist<<<ebl, 256, 0, stream>>>(ei, flag, hist, E);
  k_scan<<<1, 256, 0, stream>>>(hist, curs, N);
  k_scatter<<<ebl, 256, 0, stream>>>(ei, flag, ea, curs, srcS, dstS, eaS, E);
  k_node_proj<<<N, 256, 0, stream>>>(x, a, np_w, np_b, h, N);
  k_wcomb<<<24, 256, 0, stream>>>(em_w2, lin_w, wcTh, wcTl);
  k_beta<<<3, 256, 0, stream>>>(lin_w, lin_b, em_b2, beta);
  k_transp<<<dim3(4, 4, 3), 256, 0, stream>>>(m_w1, w1Th, w1Tl);
  k_transp<<<dim3(4, 4, 3), 256, 0, stream>>>(m_w2, w2Th, w2Tl);

  int n4 = N * H / 4;
  for (int l = 0; l < 3; l++) {
    k_zero<<<(n4 + 255) / 256, 256, 0, stream>>>((float4*)agg, n4);
    k_edge_mfma<<<E / TE, 1024, 0, stream>>>(eaS, em_w1, em_b1,
                                             wcTh + (size_t)l * H * H,
                                             beta + (size_t)l * H,
                                             h, agg, srcS, dstS);
    k_node_mfma<<<N / 32, 256, 0, stream>>>(h, agg,
                                            w1Th + (size_t)l * H * H,
                                            m_b1 + (size_t)l * H,
                                            w2Th + (size_t)l * H * H,
                                            m_b2 + (size_t)l * H,
                                            ln_g + (size_t)l * H, ln_b + (size_t)l * H);
  }
  int g4 = B * H / 4;
  k_zero<<<(g4 + 255) / 256, 256, 0, stream>>>((float4*)g, g4);
  k_pool<<<N / 64, 256, 0, stream>>>(h, g, n);
  k_head<<<B, 256, 0, stream>>>(g, hd_w1, hd_b1, hd_w2, hd_b2, out, n);
}

// Round 10
// 856.891 us; speedup vs baseline: 1.2855x; 1.0375x over previous
//
#include <hip/hip_runtime.h>
#include <hip/hip_bf16.h>

#define H 256
#define LN_EPS 1e-5f
#define PITCH 264   // bf16 elements per LDS A-row (256 + 8 pad), 528 B
#define TE 128      // edges per tile (edge kernel)

typedef __attribute__((ext_vector_type(8))) short bf16x8;   // 8 bf16 = 4 VGPRs
typedef __attribute__((ext_vector_type(4))) float f32x4;    // MFMA 16x16 accum

// ---------- helpers ----------
__device__ __forceinline__ float bf2f(unsigned short u) {
  union { unsigned int i; float f; } v; v.i = ((unsigned int)u) << 16; return v.f;
}
__device__ __forceinline__ unsigned short f2bf(float f) {
  union { float f; unsigned int i; } v; v.f = f;
  unsigned int x = v.i;
  return (unsigned short)((x + 0x7fffu + ((x >> 16) & 1u)) >> 16);  // RNE
}
// packed pair: low 16 = a, high 16 = b (RNE, single v_cvt_pk_bf16_f32)
__device__ __forceinline__ unsigned int pack2bf(float a, float b) {
  __hip_bfloat162 t = __float22bfloat162_rn(make_float2(a, b));
  unsigned int u;
  __builtin_memcpy(&u, &t, 4);
  return u;
}
// single value via the same HW cvt (1 instruction, RNE)
__device__ __forceinline__ unsigned short f2bf1(float a) {
  return (unsigned short)pack2bf(a, a);
}
__device__ __forceinline__ void fsplit(float v, unsigned short& hi, unsigned short& lo) {
  hi = f2bf(v);
  lo = f2bf(v - bf2f(hi));
}

// fp32 register-tiled GEMM core (precompute only)
__device__ __forceinline__ void gemm_tile(const float* __restrict__ sA,
                                          const float* __restrict__ W,
                                          int lane_j, int rg, float acc[8][4]) {
#pragma unroll
  for (int mm = 0; mm < 8; mm++)
#pragma unroll
    for (int cc = 0; cc < 4; cc++) acc[mm][cc] = 0.f;
  for (int k = 0; k < H; k += 4) {
    float tvf[8][4];
#pragma unroll
    for (int mm = 0; mm < 8; mm++)
      *(float4*)&tvf[mm][0] = *(const float4*)&sA[(rg * 8 + mm) * H + k];
#pragma unroll
    for (int kk = 0; kk < 4; kk++) {
      const float* wr = W + (k + kk) * H + lane_j;
      float w0 = wr[0], w1 = wr[64], w2 = wr[128], w3 = wr[192];
#pragma unroll
      for (int mm = 0; mm < 8; mm++) {
        float av = tvf[mm][kk];
        acc[mm][0] = fmaf(av, w0, acc[mm][0]);
        acc[mm][1] = fmaf(av, w1, acc[mm][1]);
        acc[mm][2] = fmaf(av, w2, acc[mm][2]);
        acc[mm][3] = fmaf(av, w3, acc[mm][3]);
      }
    }
  }
}

// ---------- precompute kernels ----------

__global__ void k_detect(const int* __restrict__ ei, int* __restrict__ flag) {
  if (threadIdx.x == 0 && blockIdx.x == 0)
    *flag = (ei[1] == 0 && ei[3] == 0 && ei[5] == 0 && ei[7] == 0) ? 1 : 0;
}

__global__ __launch_bounds__(256) void k_zero(float4* __restrict__ p, int n4) {
  int i = blockIdx.x * 256 + threadIdx.x;
  if (i < n4) p[i] = make_float4(0.f, 0.f, 0.f, 0.f);
}

// dst histogram
__global__ __launch_bounds__(256) void k_hist(
    const void* __restrict__ ei, const int* __restrict__ flag64,
    int* __restrict__ hist, int E) {
  int e = blockIdx.x * 256 + threadIdx.x;
  if (e >= E) return;
  int d = (*flag64) ? (int)((const long long*)ei)[(size_t)E + e]
                    : ((const int*)ei)[(size_t)E + e];
  atomicAdd(&hist[d], 1);
}

// exclusive prefix sum over hist[N] -> cursor[N] (single block, 256 threads)
__global__ __launch_bounds__(256) void k_scan(
    const int* __restrict__ hist, int* __restrict__ cursor, int N) {
  __shared__ int part[256];
  int tid = threadIdx.x;
  int chunk = (N + 255) / 256;
  int s = 0;
  for (int i = 0; i < chunk; i++) {
    int idx = tid * chunk + i;
    if (idx < N) s += hist[idx];
  }
  part[tid] = s;
  __syncthreads();
  for (int off = 1; off < 256; off <<= 1) {
    int v = (tid >= off) ? part[tid - off] : 0;
    __syncthreads();
    part[tid] += v;
    __syncthreads();
  }
  int excl = (tid == 0) ? 0 : part[tid - 1];
  for (int i = 0; i < chunk; i++) {
    int idx = tid * chunk + i;
    if (idx < N) {
      cursor[idx] = excl;
      excl += hist[idx];
    }
  }
}

// scatter edges into dst-sorted order (src, dst, edge_attr)
__global__ __launch_bounds__(256) void k_scatter(
    const void* __restrict__ ei, const int* __restrict__ flag64,
    const float* __restrict__ ea, int* __restrict__ cursor,
    int* __restrict__ srcS, int* __restrict__ dstS, float* __restrict__ eaS, int E) {
  int e = blockIdx.x * 256 + threadIdx.x;
  if (e >= E) return;
  int is64 = *flag64;
  int s = is64 ? (int)((const long long*)ei)[e] : ((const int*)ei)[e];
  int d = is64 ? (int)((const long long*)ei)[(size_t)E + e]
               : ((const int*)ei)[(size_t)E + e];
  int p = atomicAdd(&cursor[d], 1);
  srcS[p] = s;
  dstS[p] = d;
  ((float4*)eaS)[p] = ((const float4*)ea)[e];
}

// writes fp32 h AND the bf16 mirror hbf (consumed by the edge gather)
__global__ __launch_bounds__(256) void k_node_proj(
    const float* __restrict__ x, const int* __restrict__ a,
    const float* __restrict__ w, const float* __restrict__ b,
    float* __restrict__ h, unsigned short* __restrict__ hbf, int N) {
  int node = blockIdx.x;
  int j = threadIdx.x;
  float acc = b[j];
  acc = fmaf(x[node * 3 + 0], w[0 * H + j], acc);
  acc = fmaf(x[node * 3 + 1], w[1 * H + j], acc);
  acc = fmaf(x[node * 3 + 2], w[2 * H + j], acc);
  acc = fmaf((float)a[node], w[3 * H + j], acc);
  float v = fmaxf(acc, 0.f);
  h[(size_t)node * H + j] = v;
  hbf[(size_t)node * H + j] = f2bf1(v);
}

// WtC[l][j][k] = (em_w2 @ lin_w[l])[k][j], hi/lo bf16 planes
__global__ __launch_bounds__(256, 2) void k_wcomb(
    const float* __restrict__ w2, const float* __restrict__ lin_w,
    unsigned short* __restrict__ wcTh, unsigned short* __restrict__ wcTl) {
  __shared__ __align__(16) float sA[32 * H];
  int l = blockIdx.x >> 3, tile = blockIdx.x & 7;
  int tid = threadIdx.x;
  const float4* src = (const float4*)(w2 + (size_t)tile * 32 * H);
#pragma unroll
  for (int it = 0; it < 8; it++) {
    int vi = it * 256 + tid;
    *(float4*)&sA[vi * 4] = src[vi];
  }
  __syncthreads();
  int lane_j = tid & 63, rg = tid >> 6;
  float acc[8][4];
  gemm_tile(sA, lin_w + (size_t)l * H * H, lane_j, rg, acc);
  unsigned short* oh = wcTh + (size_t)l * H * H;
  unsigned short* ol = wcTl + (size_t)l * H * H;
#pragma unroll
  for (int cc = 0; cc < 4; cc++) {
    int j = lane_j + 64 * cc;
#pragma unroll
    for (int mm = 0; mm < 8; mm++) {
      int k = tile * 32 + rg * 8 + mm;
      unsigned short hi, lo;
      fsplit(acc[mm][cc], hi, lo);
      oh[(size_t)j * H + k] = hi;
      ol[(size_t)j * H + k] = lo;
    }
  }
}

// beta[l] = em_b2 @ lin_w[l] + lin_b[l]
__global__ __launch_bounds__(256) void k_beta(
    const float* __restrict__ lin_w, const float* __restrict__ lin_b,
    const float* __restrict__ b2, float* __restrict__ beta) {
  int l = blockIdx.x, j = threadIdx.x;
  const float* W = lin_w + (size_t)l * H * H;
  float v = lin_b[l * H + j];
  for (int k = 0; k < H; k++) v = fmaf(b2[k], W[k * H + j], v);
  beta[l * H + j] = v;
}

// out_{h,l}[l][n][k] = bf16split(in[l][k][n])
__global__ __launch_bounds__(256) void k_transp(
    const float* __restrict__ in,
    unsigned short* __restrict__ outh, unsigned short* __restrict__ outl) {
  int l = blockIdx.z;
  int kb = blockIdx.x * 64, nb = blockIdx.y * 64;
  int tid = threadIdx.x;
  __shared__ float T[64][65];
  const float* src = in + (size_t)l * H * H;
#pragma unroll
  for (int it = 0; it < 16; it++) {
    int idx = it * 256 + tid;
    int kl = idx >> 6, nl = idx & 63;
    T[kl][nl] = src[(size_t)(kb + kl) * H + nb + nl];
  }
  __syncthreads();
  unsigned short* dh = outh + (size_t)l * H * H;
  unsigned short* dl = outl + (size_t)l * H * H;
#pragma unroll
  for (int it = 0; it < 8; it++) {
    int u = it * 256 + tid;
    int nl = u >> 5, k2 = (u & 31) * 2;
    unsigned short h0, l0, h1, l1;
    fsplit(T[k2][nl], h0, l0);
    fsplit(T[k2 + 1][nl], h1, l1);
    size_t o = (size_t)(nb + nl) * H + kb + k2;
    *(unsigned int*)&dh[o] = (unsigned int)h0 | ((unsigned int)h1 << 16);
    *(unsigned int*)&dl[o] = (unsigned int)l0 | ((unsigned int)l1 << 16);
  }
}

// ---------- per-layer MFMA kernels ----------

// Edge (dst-sorted), tile = TE(128) edges x 256 cols, 16 waves x 1024 thr.
// Wave owns ONE col-group x ALL 8 row-groups: acc[8]=32 regs, single
// ah/bhf live -> 64-reg cap of (1024,8) holds -> 2 blk/CU = 32 waves (R9).
// R10: gather reads the bf16 mirror hbf (producer-side RNE conversion,
// bit-identical to R9's in-register pack) -> 2B/elem, half fabric traffic,
// no cvt in the gather phase.
__global__ __launch_bounds__(1024, 8) void k_edge_mfma(
    const float* __restrict__ eaS,
    const float* __restrict__ w1, const float* __restrict__ b1,
    const unsigned short* __restrict__ Wth,
    const float* __restrict__ beta,
    const unsigned short* __restrict__ hbf, float* __restrict__ agg,
    const int* __restrict__ srcS, const int* __restrict__ dstS) {
  __shared__ __align__(16) unsigned short sAh[TE * PITCH];  // 67584 B, A-tile / bf16 elbuf
  __shared__ __align__(16) float sEA[TE * 4];               // 2048 B
  __shared__ int sSrc[TE];
  __shared__ int sDst[TE];
  int tid = threadIdx.x;
  int base = blockIdx.x * TE;
  if (tid < TE) {
    sSrc[tid] = srcS[base + tid];
  } else if (tid < 2 * TE) {
    sDst[tid - TE] = dstS[base + tid - TE];
  } else if (tid < 3 * TE) {
    int t = tid - 2 * TE;
    ((float4*)sEA)[t] = ((const float4*)(eaS + (size_t)base * 4))[t];
  }
  __syncthreads();
  {  // t = relu(eaS @ w1 + b1) -> bf16 hi plane (col pair, 16 rows/thread)
    int j2 = (tid & 127) * 2;
    int r0 = (tid >> 7) * 16;          // 8 groups x 16 rows = 128 rows
    float wv0[4], wv1[4];
#pragma unroll
    for (int q = 0; q < 4; q++) { wv0[q] = w1[q * H + j2]; wv1[q] = w1[q * H + j2 + 1]; }
    float bb0 = b1[j2], bb1 = b1[j2 + 1];
#pragma unroll
    for (int m = r0; m < r0 + 16; m++) {
      float t0 = bb0, t1 = bb1;
#pragma unroll
      for (int q = 0; q < 4; q++) {
        float eav = sEA[m * 4 + q];
        t0 = fmaf(eav, wv0[q], t0);
        t1 = fmaf(eav, wv1[q], t1);
      }
      *(unsigned int*)&sAh[m * PITCH + j2] = pack2bf(fmaxf(t0, 0.f), fmaxf(t1, 0.f));
    }
  }
  __syncthreads();
  int lane = tid & 63, wv = tid >> 6;           // wv in 0..15 = col-group
  int lane15 = lane & 15, quad = lane >> 4;
  f32x4 acc[8];
#pragma unroll
  for (int i = 0; i < 8; i++) acc[i] = (f32x4){0.f, 0.f, 0.f, 0.f};
  const unsigned short* aph = sAh + lane15 * PITCH + quad * 8;
  const unsigned short* bph = Wth + (size_t)(wv * 16 + lane15) * H + quad * 8;
#pragma unroll
  for (int st = 0; st < 8; st++) {
    bf16x8 bhf = *(const bf16x8*)(bph + st * 32);
#pragma unroll
    for (int rg = 0; rg < 8; rg++) {
      bf16x8 ah = *(const bf16x8*)(aph + rg * 16 * PITCH + st * 32);
      acc[rg] = __builtin_amdgcn_mfma_f32_16x16x32_bf16(ah, bhf, acc[rg], 0, 0, 0);
    }
  }
  float bv = beta[wv * 16 + lane15];
  __syncthreads();  // all waves done reading A; sAh becomes bf16 elbuf
  // elbuf write first: acc dies here (never co-live with hvp below)
#pragma unroll
  for (int rg = 0; rg < 8; rg++) {
#pragma unroll
    for (int r = 0; r < 4; r++) {
      int row = rg * 16 + quad * 4 + r;
      sAh[row * PITCH + wv * 16 + lane15] = f2bf1(acc[rg][r] + bv);
    }
  }
  // coalesced bf16 h-gather: one contiguous 128B run per row per wave;
  // pairs packed with one lshl_or each. Loads drain under the barrier.
  int jcol = tid & 255, quarter = tid >> 8;
  const int* msrc = sSrc + quarter * 32;
  unsigned int hvp[16];
#pragma unroll
  for (int p = 0; p < 16; p++) {
    unsigned int u0 = hbf[(size_t)msrc[2 * p] * H + jcol];
    unsigned int u1 = hbf[(size_t)msrc[2 * p + 1] * H + jcol];
    hvp[p] = u0 | (u1 << 16);
  }
  __syncthreads();
  // segment-reduced scatter: thread (quarter,jcol) walks its 32 dst-sorted rows.
  {
    const int* mdst = sDst + quarter * 32;
    float run = 0.f;
    int prev = mdst[0];
#pragma unroll
    for (int m = 0; m < 32; m++) {
      int d = mdst[m];
      unsigned int hp = hvp[m >> 1];
      unsigned short hu = (m & 1) ? (unsigned short)(hp >> 16) : (unsigned short)hp;
      float msg = fmaxf(bf2f(hu) + bf2f(sAh[(quarter * 32 + m) * PITCH + jcol]), 0.f);
      if (d != prev) {
        atomicAdd(&agg[(size_t)prev * H + jcol], run);
        run = 0.f;
        prev = d;
      }
      run += msg;
    }
    atomicAdd(&agg[(size_t)prev * H + jcol], run);
  }
}

// Node: z=h+agg; z1=relu(z@w1+b1); z2=z1@w2+b2; LN; h += relu(LN).
// R10 geometry (= R9 edge recipe): 64-row tile, 1024 thr x 16 waves, wave
// owns ONE 16-col group x ALL 4 row-groups -> acc[4]=16 regs, single
// ah/bhf live -> fits 64-reg cap of (1024,8) -> 2 blk/CU = 32 waves (100%).
// Grid N/64 = 512 = exactly one full round. LN via [64][16] LDS partials.
// Also writes the bf16 mirror hbf for the next layer's edge gather.
__global__ __launch_bounds__(1024, 8) void k_node_mfma(
    float* __restrict__ h, unsigned short* __restrict__ hbf,
    const float* __restrict__ agg,
    const unsigned short* __restrict__ w1Th, const float* __restrict__ b1,
    const unsigned short* __restrict__ w2Th, const float* __restrict__ b2,
    const float* __restrict__ lng, const float* __restrict__ lnb) {
  __shared__ __align__(16) unsigned short sAh[64 * PITCH];  // 33792 B
  __shared__ float sPartS[64][16];
  __shared__ float sPartQ[64][16];
  __shared__ float sMu[64];
  __shared__ float sRstd[64];
  int tid = threadIdx.x;
  int base = blockIdx.x * 64;
  const float4* h4 = (const float4*)(h + (size_t)base * H);
  const float4* a4 = (const float4*)(agg + (size_t)base * H);
#pragma unroll
  for (int it = 0; it < 4; it++) {  // all 64 rows (4096 float4)
    int vi = it * 1024 + tid;
    int row = vi >> 6, c4 = (vi & 63) * 4;
    float4 hv = h4[vi], av = a4[vi];
    uint2 uh;
    uh.x = pack2bf(hv.x + av.x, hv.y + av.y);
    uh.y = pack2bf(hv.z + av.z, hv.w + av.w);
    *(uint2*)&sAh[row * PITCH + c4] = uh;
  }
  __syncthreads();
  int lane = tid & 63, wv = tid >> 6;          // wv 0..15 = col-group
  int lane15 = lane & 15, quad = lane >> 4;
  int col = wv * 16 + lane15;                  // this thread's output column
  const unsigned short* aph = sAh + lane15 * PITCH + quad * 8;
  // ---- GEMM1: z1 = relu(z @ w1 + b1), acc[rg]
  f32x4 acc[4];
#pragma unroll
  for (int i = 0; i < 4; i++) acc[i] = (f32x4){0.f, 0.f, 0.f, 0.f};
  {
    const unsigned short* bph = w1Th + (size_t)col * H + quad * 8;
#pragma unroll
    for (int st = 0; st < 8; st++) {
      bf16x8 bhf = *(const bf16x8*)(bph + st * 32);
#pragma unroll
      for (int rg = 0; rg < 4; rg++) {
        bf16x8 ah = *(const bf16x8*)(aph + rg * 16 * PITCH + st * 32);
        acc[rg] = __builtin_amdgcn_mfma_f32_16x16x32_bf16(ah, bhf, acc[rg], 0, 0, 0);
      }
    }
  }
  float b1v = b1[col];
  __syncthreads();  // all waves done reading z
#pragma unroll
  for (int rg = 0; rg < 4; rg++)
#pragma unroll
    for (int r = 0; r < 4; r++) {
      int row = rg * 16 + quad * 4 + r;
      sAh[row * PITCH + col] = f2bf1(fmaxf(acc[rg][r] + b1v, 0.f));
    }
  __syncthreads();
  // ---- GEMM2: z2 = z1 @ w2 + b2, acc2[rg]
  f32x4 acc2[4];
#pragma unroll
  for (int i = 0; i < 4; i++) acc2[i] = (f32x4){0.f, 0.f, 0.f, 0.f};
  {
    const unsigned short* bph = w2Th + (size_t)col * H + quad * 8;
#pragma unroll
    for (int st = 0; st < 8; st++) {
      bf16x8 bhf = *(const bf16x8*)(bph + st * 32);
#pragma unroll
      for (int rg = 0; rg < 4; rg++) {
        bf16x8 ah = *(const bf16x8*)(aph + rg * 16 * PITCH + st * 32);
        acc2[rg] = __builtin_amdgcn_mfma_f32_16x16x32_bf16(ah, bhf, acc2[rg], 0, 0, 0);
      }
    }
  }
  float b2v = b2[col], gv = lng[col], bbv = lnb[col];
  // ---- LN partials: per row, reduce this wave's 16 cols
#pragma unroll
  for (int rg = 0; rg < 4; rg++)
#pragma unroll
    for (int r = 0; r < 4; r++) {
      int row = rg * 16 + quad * 4 + r;
      float z2 = acc2[rg][r] + b2v;
      float s = z2, ss = z2 * z2;
      s += __shfl_xor(s, 1, 64); ss += __shfl_xor(ss, 1, 64);
      s += __shfl_xor(s, 2, 64); ss += __shfl_xor(ss, 2, 64);
      s += __shfl_xor(s, 4, 64); ss += __shfl_xor(ss, 4, 64);
      s += __shfl_xor(s, 8, 64); ss += __shfl_xor(ss, 8, 64);
      if (lane15 == 0) { sPartS[row][wv] = s; sPartQ[row][wv] = ss; }
    }
  __syncthreads();
  if (tid < 64) {
    float s = 0.f, ss = 0.f;
#pragma unroll
    for (int w = 0; w < 16; w++) { s += sPartS[tid][w]; ss += sPartQ[tid][w]; }
    float mu = s * (1.f / H);
    float var = ss * (1.f / H) - mu * mu;
    sMu[tid] = mu;
    sRstd[tid] = rsqrtf(var + LN_EPS);
  }
  __syncthreads();
  // ---- apply LN + residual; write fp32 h and bf16 mirror
#pragma unroll
  for (int rg = 0; rg < 4; rg++)
#pragma unroll
    for (int r = 0; r < 4; r++) {
      int row = rg * 16 + quad * 4 + r;
      float mu = sMu[row], rstd = sRstd[row];
      size_t o = (size_t)(base + row) * H + col;
      float z2 = acc2[rg][r] + b2v;
      float v = fmaf((z2 - mu) * rstd, gv, bbv);
      float hn = h[o] + fmaxf(v, 0.f);
      h[o] = hn;
      hbf[o] = f2bf1(hn);
    }
}

// Partial mean-pool: block sums 64 rows into g[b][.] via atomics (fully parallel).
__global__ __launch_bounds__(256) void k_pool(
    const float* __restrict__ h, float* __restrict__ g, int n) {
  int tid = threadIdx.x;
  int row0 = blockIdx.x * 64;
  int b = row0 / n;                       // 64 | n, block never straddles graphs
  const float* hb = h + (size_t)row0 * H;
  float s0 = 0.f, s1 = 0.f, s2 = 0.f, s3 = 0.f;
  for (int i = 0; i < 64; i += 4) {
    s0 += hb[(size_t)(i + 0) * H + tid];
    s1 += hb[(size_t)(i + 1) * H + tid];
    s2 += hb[(size_t)(i + 2) * H + tid];
    s3 += hb[(size_t)(i + 3) * H + tid];
  }
  atomicAdd(&g[(size_t)b * H + tid], s0 + s1 + s2 + s3);
}

// Head MLP from pooled g. One block per graph.
__global__ __launch_bounds__(256) void k_head(
    const float* __restrict__ g,
    const float* __restrict__ w1, const float* __restrict__ b1,
    const float* __restrict__ w2, const float* __restrict__ b2,
    float* __restrict__ out, int n) {
  __shared__ float sG[H];
  __shared__ float sT[H];
  __shared__ float sR[4];
  int b = blockIdx.x, tid = threadIdx.x;
  sG[tid] = g[(size_t)b * H + tid] / (float)n;
  __syncthreads();
  float t = b1[tid];
  for (int k = 0; k < H; k++) t = fmaf(sG[k], w1[k * H + tid], t);
  sT[tid] = fmaxf(t, 0.f);
  __syncthreads();
  float p = sT[tid] * w2[tid];
#pragma unroll
  for (int off = 32; off > 0; off >>= 1) p += __shfl_xor(p, off, 64);
  if ((tid & 63) == 0) sR[tid >> 6] = p;
  __syncthreads();
  if (tid == 0) out[b] = sR[0] + sR[1] + sR[2] + sR[3] + b2[0];
}

// ---------- launcher ----------
extern "C" void kernel_launch(void* const* d_in, const int* in_sizes, int n_in,
                              void* d_out, int out_size, void* d_ws, size_t ws_size,
                              hipStream_t stream) {
  const float* x      = (const float*)d_in[0];
  const float* ea     = (const float*)d_in[1];
  const void*  ei     = d_in[2];
  const int*   a      = (const int*)d_in[3];
  const float* np_w   = (const float*)d_in[4];
  const float* np_b   = (const float*)d_in[5];
  const float* em_w1  = (const float*)d_in[6];
  const float* em_b1  = (const float*)d_in[7];
  const float* em_w2  = (const float*)d_in[8];
  const float* em_b2  = (const float*)d_in[9];
  const float* lin_w  = (const float*)d_in[10];
  const float* lin_b  = (const float*)d_in[11];
  const float* m_w1   = (const float*)d_in[12];
  const float* m_b1   = (const float*)d_in[13];
  const float* m_w2   = (const float*)d_in[14];
  const float* m_b2   = (const float*)d_in[15];
  const float* ln_g   = (const float*)d_in[16];
  const float* ln_b   = (const float*)d_in[17];
  const float* hd_w1  = (const float*)d_in[18];
  const float* hd_b1  = (const float*)d_in[19];
  const float* hd_w2  = (const float*)d_in[20];
  const float* hd_b2  = (const float*)d_in[21];

  int N = in_sizes[0] / 3;
  int E = in_sizes[1] / 4;
  int B = out_size;
  int n = N / B;

  // workspace layout (~100 MB)
  char* ws = (char*)d_ws;
  size_t off = 0;
  auto alloc = [&](size_t bytes) {
    char* p = ws + off;
    off += (bytes + 255) & ~(size_t)255;
    return p;
  };
  float* h    = (float*)alloc((size_t)N * H * 4);
  unsigned short* hbf = (unsigned short*)alloc((size_t)N * H * 2);
  float* agg  = (float*)alloc((size_t)N * H * 4);
  unsigned short* wcTh = (unsigned short*)alloc((size_t)3 * H * H * 2);
  unsigned short* wcTl = (unsigned short*)alloc((size_t)3 * H * H * 2);
  unsigned short* w1Th = (unsigned short*)alloc((size_t)3 * H * H * 2);
  unsigned short* w1Tl = (unsigned short*)alloc((size_t)3 * H * H * 2);
  unsigned short* w2Th = (unsigned short*)alloc((size_t)3 * H * H * 2);
  unsigned short* w2Tl = (unsigned short*)alloc((size_t)3 * H * H * 2);
  float* beta  = (float*)alloc(3 * H * 4);
  int*   flag  = (int*)alloc(4);
  int*   hist  = (int*)alloc((size_t)N * 4);
  int*   curs  = (int*)alloc((size_t)N * 4);
  int*   srcS  = (int*)alloc((size_t)E * 4);
  int*   dstS  = (int*)alloc((size_t)E * 4);
  float* eaS   = (float*)alloc((size_t)E * 4 * 4);
  float* g     = (float*)alloc((size_t)B * H * 4);

  float* out = (float*)d_out;
  int ebl = (E + 255) / 256;

  k_detect<<<1, 64, 0, stream>>>((const int*)ei, flag);
  k_zero<<<(N + 1023) / 1024, 256, 0, stream>>>((float4*)hist, N / 4);
  k_hist<<<ebl, 256, 0, stream>>>(ei, flag, hist, E);
  k_scan<<<1, 256, 0, stream>>>(hist, curs, N);
  k_scatter<<<ebl, 256, 0, stream>>>(ei, flag, ea, curs, srcS, dstS, eaS, E);
  k_node_proj<<<N, 256, 0, stream>>>(x, a, np_w, np_b, h, hbf, N);
  k_wcomb<<<24, 256, 0, stream>>>(em_w2, lin_w, wcTh, wcTl);
  k_beta<<<3, 256, 0, stream>>>(lin_w, lin_b, em_b2, beta);
  k_transp<<<dim3(4, 4, 3), 256, 0, stream>>>(m_w1, w1Th, w1Tl);
  k_transp<<<dim3(4, 4, 3), 256, 0, stream>>>(m_w2, w2Th, w2Tl);

  int n4 = N * H / 4;
  for (int l = 0; l < 3; l++) {
    k_zero<<<(n4 + 255) / 256, 256, 0, stream>>>((float4*)agg, n4);
    k_edge_mfma<<<E / TE, 1024, 0, stream>>>(eaS, em_w1, em_b1,
                                             wcTh + (size_t)l * H * H,
                                             beta + (size_t)l * H,
                                             hbf, agg, srcS, dstS);
    k_node_mfma<<<N / 64, 1024, 0, stream>>>(h, hbf, agg,
                                             w1Th + (size_t)l * H * H,
                                             m_b1 + (size_t)l * H,
                                             w2Th + (size_t)l * H * H,
                                             m_b2 + (size_t)l * H,
                                             ln_g + (size_t)l * H, ln_b + (size_t)l * H);
  }
  int g4 = B * H / 4;
  k_zero<<<(g4 + 255) / 256, 256, 0, stream>>>((float4*)g, g4);
  k_pool<<<N / 64, 256, 0, stream>>>(h, g, n);
  k_head<<<B, 256, 0, stream>>>(g, hd_w1, hd_b1, hd_w2, hd_b2, out, n);
}